// Round 5
// baseline (4222.277 us; speedup 1.0000x reference)
//
#include <hip/hip_runtime.h>

// N=100000 nodes, E=1600000 edges, IN=128, H=64, R=32, B=512
constexpr int HD     = 64;
constexpr int RNUM   = 32;
constexpr int STRIDE = 768;   // edge-grid per block
constexpr int NMAX   = 96;    // max nodes per LDS group
constexpr int CAPE   = 1024;  // max edges per in-LDS sort sub-range

typedef __attribute__((ext_vector_type(4))) float f32x4;
typedef __attribute__((ext_vector_type(8))) short bf16x8;

#define WS_ALIGN(x) (((x) + size_t(255)) & ~size_t(255))

__device__ inline float b2f(unsigned short u) {
    return __uint_as_float(((unsigned)u) << 16);
}
__device__ inline unsigned short f2b(float f) {
    unsigned u = __float_as_uint(f);
    u = (u + 0x7FFF + ((u >> 16) & 1)) >> 16;
    return (unsigned short)u;
}
__device__ inline unsigned pack2bf(float a, float b) {
    return (unsigned)f2b(a) | ((unsigned)f2b(b) << 16);
}

// ---------------- preprocessing ----------------

// deg[dst]++ and per-edge rank within its dst
__global__ __launch_bounds__(256) void count_kernel(
    const int* __restrict__ dst, int* __restrict__ deg, int* __restrict__ rank, int E)
{
    int e = blockIdx.x * 256 + threadIdx.x;
    if (e < E) rank[e] = atomicAdd(&deg[dst[e]], 1);
}

// generic exclusive scan (3 passes)
__global__ __launch_bounds__(256) void scan1_kernel(
    const int* __restrict__ in, int* __restrict__ out, int* __restrict__ part, int n)
{
    __shared__ int ls[256];
    const int i0 = blockIdx.x * 1024 + threadIdx.x * 4;
    int v[4];
    int tot = 0;
#pragma unroll
    for (int u = 0; u < 4; ++u) {
        int x = (i0 + u < n) ? in[i0 + u] : 0;
        v[u] = tot;
        tot += x;
    }
    ls[threadIdx.x] = tot;
    __syncthreads();
    for (int off = 1; off < 256; off <<= 1) {
        int x = (threadIdx.x >= off) ? ls[threadIdx.x - off] : 0;
        __syncthreads();
        ls[threadIdx.x] += x;
        __syncthreads();
    }
    int texcl = ls[threadIdx.x] - tot;
#pragma unroll
    for (int u = 0; u < 4; ++u)
        if (i0 + u < n) out[i0 + u] = texcl + v[u];
    if (threadIdx.x == 255) part[blockIdx.x] = ls[255];
}

__global__ void scan2_kernel(int* __restrict__ part, int nb, int* __restrict__ out, int n)
{
    if (threadIdx.x == 0) {
        int acc = 0;
        for (int i = 0; i < nb; ++i) { int t = part[i]; part[i] = acc; acc += t; }
        out[n] = acc;
    }
}

__global__ __launch_bounds__(256) void scan3_kernel(
    int* __restrict__ out, const int* __restrict__ part, int n)
{
    int i = blockIdx.x * 256 + threadIdx.x;
    if (i < n) out[i] += part[blockIdx.x >> 2];
}

// block boundaries: bstart[b] = first node n with nstart[n] >= b*STRIDE
__global__ __launch_bounds__(256) void boundary_kernel(
    const int* __restrict__ nstart, int* __restrict__ bstart, int N, int nblk)
{
    int b = blockIdx.x * 256 + threadIdx.x;
    if (b > nblk) return;
    if (b == nblk) { bstart[b] = N; return; }
    int target = b * STRIDE;
    int lo = 0, hi = N;
    while (lo < hi) {
        int mid = (lo + hi) >> 1;
        if (nstart[mid] < target) lo = mid + 1; else hi = mid;
    }
    bstart[b] = lo;
}

// CSR scatter: es[nstart[d]+rank[e]] = src | (type<<17)
__global__ __launch_bounds__(256) void scatter_kernel(
    const int* __restrict__ src, const int* __restrict__ dst, const int* __restrict__ et,
    const int* __restrict__ rank, const int* __restrict__ nstart,
    int* __restrict__ es, int E)
{
    int e = blockIdx.x * 256 + threadIdx.x;
    if (e < E)
        es[nstart[dst[e]] + rank[e]] = src[e] | (et[e] << 17);
}

// f32 -> bf16 convert (8 elems/thread)
__global__ __launch_bounds__(256) void tobf16_kernel(
    const float* __restrict__ in, unsigned short* __restrict__ out, int total8)
{
    int i = blockIdx.x * 256 + threadIdx.x;
    if (i >= total8) return;
    const float4* ip = (const float4*)(in + (size_t)i * 8);
    float4 a = ip[0], b = ip[1];
    uint4 o;
    o.x = pack2bf(a.x, a.y); o.y = pack2bf(a.z, a.w);
    o.z = pack2bf(b.x, b.y); o.w = pack2bf(b.z, b.w);
    *(uint4*)(out + (size_t)i * 8) = o;
}

// pre-permute W (+Wroot as t=32) into MFMA A-fragment layout, bf16:
// wfrag[t][ks][jt][lane][8] = W[t][ks*32+(lane>>4)*8+jj][jt*16+(lane&15)]
template<int K>
__global__ __launch_bounds__(256) void wfrag_kernel(
    const float* __restrict__ W, const float* __restrict__ Root,
    unsigned short* __restrict__ wfrag)
{
    constexpr int KS = K / 32;
    int idx = blockIdx.x * 256 + threadIdx.x;
    int total = 33 * KS * 4 * 64;
    if (idx >= total) return;
    int lane = idx & 63;
    int tmp = idx >> 6;
    int jt = tmp & 3; tmp >>= 2;
    int ks = tmp % KS;
    int t = tmp / KS;
    int col = jt * 16 + (lane & 15);
    int kb = ks * 32 + (lane >> 4) * 8;
    const float* Wp = (t < RNUM) ? (W + ((size_t)t * K + kb) * HD + col)
                                 : (Root + (size_t)kb * HD + col);
    uint4 o;
    o.x = pack2bf(Wp[0 * HD], Wp[1 * HD]);
    o.y = pack2bf(Wp[2 * HD], Wp[3 * HD]);
    o.z = pack2bf(Wp[4 * HD], Wp[5 * HD]);
    o.w = pack2bf(Wp[6 * HD], Wp[7 * HD]);
    *(uint4*)(wfrag + (size_t)idx * 8) = o;
}

__device__ inline int bsearch_dl(const int* ns_l, int NL, int e)
{
    int lo = 0, hi = NL - 1;
    while (lo < hi) {
        int mid = (lo + hi + 1) >> 1;
        if (ns_l[mid] <= e) lo = mid; else hi = mid - 1;
    }
    return lo;
}

// fused RGCN layer: per-block node range; in-LDS type sort; MFMA per 16-edge
// single-type batch; scaled f32 LDS accumulation; bias+relu epilogue.
template<int K>
__global__ __launch_bounds__(256) void fused_kernel(
    const unsigned short* __restrict__ xb, const int* __restrict__ es,
    const int* __restrict__ nstart, const int* __restrict__ bstart,
    const unsigned short* __restrict__ wfrag, const float* __restrict__ bias,
    unsigned short* __restrict__ hout, int N)
{
    constexpr int KS = K / 32;
    __shared__ int ns_l[NMAX + 1];
    __shared__ int cnts[NMAX * 33];      // int counts -> f32 inverse (bits in place)
    __shared__ float hacc[NMAX * 66];
    __shared__ int sorted[CAPE];
    __shared__ int tcnt[33], tbase[33], tcur[33];
    __shared__ int bdesc[CAPE / 16 + 48];
    __shared__ int nb_s;

    const int tid = threadIdx.x;
    const int lane = tid & 63;
    const int wid = tid >> 6;
    const int n0b = bstart[blockIdx.x];
    const int n1b = bstart[blockIdx.x + 1];
    if (n0b >= n1b) return;

    for (int g0 = n0b; g0 < n1b; g0 += NMAX) {
        const int g1 = (g0 + NMAX < n1b) ? g0 + NMAX : n1b;
        const int NL = g1 - g0;
        for (int i = tid; i <= NL; i += 256) ns_l[i] = nstart[g0 + i];
        for (int i = tid; i < NL * 33; i += 256) cnts[i] = 0;
        for (int i = tid; i < NL * 66; i += 256) hacc[i] = 0.f;
        __syncthreads();
        const int e0 = ns_l[0], e1 = ns_l[NL];

        // per-(node,type) counts over full group span
        for (int e = e0 + tid; e < e1; e += 256) {
            int v = es[e];
            int t = (v >> 17) & 31;
            int dl = bsearch_dl(ns_l, NL, e);
            atomicAdd(&cnts[dl * 33 + t], 1);
        }
        __syncthreads();
        for (int i = tid; i < NL * 33; i += 256) {
            int c = cnts[i];
            cnts[i] = __float_as_int(1.0f / (float)(c > 1 ? c : 1));
        }

        // sub-range loop (>=1 iteration so root batches always run)
        int s0 = e0;
        while (true) {
            const bool lastSR = (s0 + CAPE >= e1);
            const int s1 = lastSR ? e1 : s0 + CAPE;
            if (tid < 33) tcnt[tid] = 0;
            __syncthreads();
            for (int e = s0 + tid; e < s1; e += 256)
                atomicAdd(&tcnt[(es[e] >> 17) & 31], 1);
            __syncthreads();
            if (tid == 0) {
                int nb = 0, acc = 0;
                for (int t = 0; t < 32; ++t) {
                    tbase[t] = acc;
                    for (int c = 0; c < tcnt[t]; c += 16)
                        bdesc[nb++] = (t << 12) | (acc + c);
                    acc += tcnt[t];
                }
                if (lastSR)
                    for (int c = 0; c < NL; c += 16)
                        bdesc[nb++] = (32 << 12) | c;
                nb_s = nb;
            }
            __syncthreads();
            if (tid < 32) tcur[tid] = tbase[tid];
            __syncthreads();
            for (int e = s0 + tid; e < s1; e += 256) {
                int v = es[e];
                int t = (v >> 17) & 31;
                int dl = bsearch_dl(ns_l, NL, e);
                int pos = atomicAdd(&tcur[t], 1);
                sorted[pos] = (v & 0x1FFFF) | (dl << 17);
            }
            __syncthreads();

            const int nb = nb_s;
            for (int bi = wid; bi < nb; bi += 4) {
                const int desc = bdesc[bi];
                const int t = desc >> 12;
                const int p0 = desc & 0xFFF;
                int sidx, dl;
                float scale;
                if (t == 32) {
                    int c = p0 + (lane & 15);
                    bool val = c < NL;
                    dl = val ? c : 0;
                    sidx = g0 + dl;
                    scale = val ? 1.f : 0.f;
                } else {
                    int end = tbase[t] + tcnt[t];
                    int c = p0 + (lane & 15);
                    bool val = c < end;
                    int sv = sorted[val ? c : p0];
                    sidx = sv & 0x1FFFF;
                    dl = (sv >> 17) & 127;
                    scale = val ? __int_as_float(cnts[dl * 33 + t]) : 0.f;
                }
                f32x4 acc[4];
#pragma unroll
                for (int jt = 0; jt < 4; ++jt) acc[jt] = (f32x4)0.0f;
                const unsigned short* wt = wfrag + (size_t)t * (KS * 2048);
                const unsigned short* xp = xb + (size_t)sidx * K + (lane >> 4) * 8;
#pragma unroll
                for (int ks = 0; ks < KS; ++ks) {
                    bf16x8 bx = *(const bf16x8*)(xp + ks * 32);
#pragma unroll
                    for (int jt = 0; jt < 4; ++jt) {
                        bf16x8 aw = *(const bf16x8*)(wt + ((size_t)((ks * 4 + jt) * 64 + lane)) * 8);
                        acc[jt] = __builtin_amdgcn_mfma_f32_16x16x32_bf16(aw, bx, acc[jt], 0, 0, 0);
                    }
                }
                const int hbase = dl * 66 + (lane >> 4) * 4;
#pragma unroll
                for (int jt = 0; jt < 4; ++jt)
#pragma unroll
                    for (int r = 0; r < 4; ++r)
                        atomicAdd(&hacc[hbase + jt * 16 + r], acc[jt][r] * scale);
            }
            __syncthreads();
            if (lastSR) break;
            s0 = s1;
        }

        // epilogue: bias + relu -> bf16
        for (int nl = wid; nl < NL; nl += 4) {
            float vv = hacc[nl * 66 + lane] + bias[lane];
            vv = fmaxf(vv, 0.f);
            hout[(size_t)(g0 + nl) * 64 + lane] = f2b(vv);
        }
        __syncthreads();
    }
}

// mean-pool h per graph; batch sorted -> register run accumulation
__global__ __launch_bounds__(256) void pool_kernel(
    const unsigned short* __restrict__ h, const int* __restrict__ batch,
    float* __restrict__ pool, float* __restrict__ gcnt, int col0, int n)
{
    const int lane = threadIdx.x & 63;
    const int wid = (blockIdx.x * 256 + threadIdx.x) >> 6;
    const int RANGE = 256;
    int n0 = wid * RANGE;
    if (n0 >= n) return;
    int n1 = n0 + RANGE;
    if (n1 > n) n1 = n;
    int cur = batch[n0];
    float acc = 0.f, c = 0.f;
    for (int i = n0; i < n1; ++i) {
        int b = batch[i];
        if (b != cur) {
            unsafeAtomicAdd(&pool[(size_t)cur * 128 + col0 + lane], acc);
            if (lane == 0) unsafeAtomicAdd(&gcnt[cur], c);
            acc = 0.f; c = 0.f; cur = b;
        }
        acc += b2f(h[(size_t)i * HD + lane]);
        c += 1.f;
    }
    unsafeAtomicAdd(&pool[(size_t)cur * 128 + col0 + lane], acc);
    if (lane == 0) unsafeAtomicAdd(&gcnt[cur], c);
}

__global__ __launch_bounds__(512) void depth_kernel(
    const float* __restrict__ depth, float* __restrict__ dnorm, int Bn)
{
    __shared__ float ls[8];
    __shared__ float smean, sstd;
    const int t = threadIdx.x, lane = t & 63, wv = t >> 6;
    float d = (t < Bn) ? depth[t] : 0.f;
    float s = d;
#pragma unroll
    for (int o = 32; o; o >>= 1) s += __shfl_down(s, o, 64);
    if (lane == 0) ls[wv] = s;
    __syncthreads();
    if (t == 0) {
        float tot = 0.f;
        for (int i = 0; i < 8; ++i) tot += ls[i];
        smean = tot / (float)Bn;
    }
    __syncthreads();
    float mean = smean;
    float df = (t < Bn) ? (d - mean) : 0.f;
    s = df * df;
#pragma unroll
    for (int o = 32; o; o >>= 1) s += __shfl_down(s, o, 64);
    __syncthreads();
    if (lane == 0) ls[wv] = s;
    __syncthreads();
    if (t == 0) {
        float tot = 0.f;
        for (int i = 0; i < 8; ++i) tot += ls[i];
        sstd = sqrtf(tot / (float)Bn);
    }
    __syncthreads();
    if (t < Bn) dnorm[t] = df / (sstd + 1e-6f);
}

__global__ __launch_bounds__(256) void regress_kernel(
    const float* __restrict__ pool, const float* __restrict__ gcnt_s,
    const float* __restrict__ gcnt_g, const float* __restrict__ dnorm,
    const float* __restrict__ rW1, const float* __restrict__ rB1,
    const float* __restrict__ rW2, const float* __restrict__ rB2,
    float* __restrict__ pred, int Bn)
{
    const int lane = threadIdx.x & 63;
    const int g = (blockIdx.x * 256 + threadIdx.x) >> 6;
    if (g >= Bn) return;
    const float is = 1.f / fmaxf(gcnt_s[g], 1.f);
    const float ig = 1.f / fmaxf(gcnt_g[g], 1.f);
    const float* pr = pool + (size_t)g * 128;
    float acc = rB1[lane];
    for (int k = 0; k < 64; ++k)
        acc = fmaf(pr[k] * is, rW1[k * 64 + lane], acc);
    for (int k = 64; k < 128; ++k)
        acc = fmaf(pr[k] * ig, rW1[k * 64 + lane], acc);
    acc = fmaf(dnorm[g], rW1[128 * 64 + lane], acc);
    float v = fmaxf(acc, 0.f) * rW2[lane];
#pragma unroll
    for (int o = 32; o; o >>= 1) v += __shfl_down(v, o, 64);
    if (lane == 0) pred[g] = v + rB2[0];
}

// ---------------- launch ----------------

extern "C" void kernel_launch(void* const* d_in, const int* in_sizes, int n_in,
                              void* d_out, int out_size, void* d_ws, size_t ws_size,
                              hipStream_t stream)
{
    const int E1 = in_sizes[2];
    const int E2 = in_sizes[6];
    const int Emax = E1 > E2 ? E1 : E2;
    const int N = in_sizes[3];
    const int IN = in_sizes[0] / N;   // 128
    const int Bn = in_sizes[8];

    const float* state_x = (const float*)d_in[0];
    const int* s_ei = (const int*)d_in[1];
    const int* s_et = (const int*)d_in[2];
    const int* s_batch = (const int*)d_in[3];
    const float* goal_x = (const float*)d_in[4];
    const int* g_ei = (const int*)d_in[5];
    const int* g_et = (const int*)d_in[6];
    const int* g_batch = (const int*)d_in[7];
    const float* depth = (const float*)d_in[8];
    const float* sW1 = (const float*)d_in[9];
    const float* sRoot1 = (const float*)d_in[10];
    const float* sB1 = (const float*)d_in[11];
    const float* sW2 = (const float*)d_in[12];
    const float* sRoot2 = (const float*)d_in[13];
    const float* sB2 = (const float*)d_in[14];
    const float* gW1 = (const float*)d_in[15];
    const float* gRoot1 = (const float*)d_in[16];
    const float* gB1 = (const float*)d_in[17];
    const float* gW2 = (const float*)d_in[18];
    const float* gRoot2 = (const float*)d_in[19];
    const float* gB2 = (const float*)d_in[20];
    const float* rW1 = (const float*)d_in[21];
    const float* rB1 = (const float*)d_in[22];
    const float* rW2 = (const float*)d_in[23];
    const float* rB2 = (const float*)d_in[24];
    float* pred = (float*)d_out;

    const int nbScan = (N + 1023) / 1024;
    const int nblkMax = (Emax + STRIDE - 1) / STRIDE;

    char* p = (char*)d_ws;
    auto alloc = [&](size_t bytes) { char* r = p; p += WS_ALIGN(bytes); return r; };
    int* deg    = (int*)alloc((size_t)N * 4);
    int* nstart = (int*)alloc((size_t)(N + 1) * 4);
    int* rank   = (int*)alloc((size_t)Emax * 4);
    int* part   = (int*)alloc((size_t)nbScan * 4);
    int* bstart = (int*)alloc((size_t)(nblkMax + 1) * 4);
    int* es     = (int*)alloc((size_t)Emax * 4);
    unsigned short* xb  = (unsigned short*)alloc((size_t)N * IN * 2);
    unsigned short* h1  = (unsigned short*)alloc((size_t)N * HD * 2);
    unsigned short* h2  = (unsigned short*)alloc((size_t)N * HD * 2);
    unsigned short* wf1 = (unsigned short*)alloc((size_t)33 * 4 * 4 * 64 * 8 * 2);
    unsigned short* wf2 = (unsigned short*)alloc((size_t)33 * 2 * 4 * 64 * 8 * 2);
    float* pool   = (float*)alloc((size_t)Bn * 128 * 4);
    float* gcnt_s = (float*)alloc((size_t)Bn * 4);
    float* gcnt_g = (float*)alloc((size_t)Bn * 4);
    float* dnorm  = (float*)alloc((size_t)Bn * 4);

    hipMemsetAsync(pool, 0, (size_t)Bn * 128 * 4, stream);
    hipMemsetAsync(gcnt_s, 0, (size_t)Bn * 4, stream);
    hipMemsetAsync(gcnt_g, 0, (size_t)Bn * 4, stream);

    for (int enc = 0; enc < 2; ++enc) {
        const float* x = enc ? goal_x : state_x;
        const int* ei = enc ? g_ei : s_ei;
        const int* et = enc ? g_et : s_et;
        const int* batch = enc ? g_batch : s_batch;
        const float* W1 = enc ? gW1 : sW1;
        const float* Root1 = enc ? gRoot1 : sRoot1;
        const float* B1 = enc ? gB1 : sB1;
        const float* W2 = enc ? gW2 : sW2;
        const float* Root2 = enc ? gRoot2 : sRoot2;
        const float* B2 = enc ? gB2 : sB2;
        float* gcnt = enc ? gcnt_g : gcnt_s;
        const int E = enc ? E2 : E1;
        const int* srcp = ei;
        const int* dstp = ei + E;
        const int ebl = (E + 255) / 256;
        const int nblk = (E + STRIDE - 1) / STRIDE;

        hipMemsetAsync(deg, 0, (size_t)N * 4, stream);

        count_kernel<<<ebl, 256, 0, stream>>>(dstp, deg, rank, E);
        scan1_kernel<<<nbScan, 256, 0, stream>>>(deg, nstart, part, N);
        scan2_kernel<<<1, 64, 0, stream>>>(part, nbScan, nstart, N);
        scan3_kernel<<<nbScan * 4, 256, 0, stream>>>(nstart, part, N);
        boundary_kernel<<<(nblk + 1 + 255) / 256, 256, 0, stream>>>(nstart, bstart, N, nblk);
        scatter_kernel<<<ebl, 256, 0, stream>>>(srcp, dstp, et, rank, nstart, es, E);

        tobf16_kernel<<<(N * IN / 8 + 255) / 256, 256, 0, stream>>>(x, xb, N * IN / 8);
        wfrag_kernel<128><<<(33 * 4 * 4 * 64 + 255) / 256, 256, 0, stream>>>(W1, Root1, wf1);
        wfrag_kernel<64><<<(33 * 2 * 4 * 64 + 255) / 256, 256, 0, stream>>>(W2, Root2, wf2);

        fused_kernel<128><<<nblk, 256, 0, stream>>>(xb, es, nstart, bstart, wf1, B1, h1, N);
        fused_kernel<64><<<nblk, 256, 0, stream>>>(h1, es, nstart, bstart, wf2, B2, h2, N);

        int pwaves = (N + 255) / 256;
        pool_kernel<<<(pwaves * 64 + 255) / 256, 256, 0, stream>>>(
            h2, batch, pool, gcnt, enc * 64, N);
    }

    depth_kernel<<<1, 512, 0, stream>>>(depth, dnorm, Bn);
    regress_kernel<<<(Bn * 64 + 255) / 256, 256, 0, stream>>>(
        pool, gcnt_s, gcnt_g, dnorm, rW1, rB1, rW2, rB2, pred, Bn);
}

// Round 6
// 2154.702 us; speedup vs baseline: 1.9596x; 1.9596x over previous
//
#include <hip/hip_runtime.h>

// N=100000 nodes, E=1600000 edges, IN=128, H=64, R=32, B=512
constexpr int HD    = 64;
constexpr int RNUM  = 32;
constexpr int WROWS = 1024;   // CSR rows per gemm block

typedef __attribute__((ext_vector_type(4))) float f32x4;
typedef __attribute__((ext_vector_type(8))) short bf16x8;

#define WS_ALIGN(x) (((x) + size_t(255)) & ~size_t(255))

__device__ inline float b2f(unsigned short u) {
    return __uint_as_float(((unsigned)u) << 16);
}
__device__ inline unsigned short f2b(float f) {
    unsigned u = __float_as_uint(f);
    u = (u + 0x7FFF + ((u >> 16) & 1)) >> 16;
    return (unsigned short)u;
}
__device__ inline unsigned pack2bf(float a, float b) {
    return (unsigned)f2b(a) | ((unsigned)f2b(b) << 16);
}

// ---------------- preprocessing ----------------

// deg[dst]++ and per-edge arrival rank within its dst
__global__ __launch_bounds__(256) void count_kernel(
    const int* __restrict__ dst, int* __restrict__ deg, int* __restrict__ rank, int E)
{
    int e = blockIdx.x * 256 + threadIdx.x;
    if (e < E) rank[e] = atomicAdd(&deg[dst[e]], 1);
}

// generic exclusive scan (3 passes)
__global__ __launch_bounds__(256) void scan1_kernel(
    const int* __restrict__ in, int* __restrict__ out, int* __restrict__ part, int n)
{
    __shared__ int ls[256];
    const int i0 = blockIdx.x * 1024 + threadIdx.x * 4;
    int v[4];
    int tot = 0;
#pragma unroll
    for (int u = 0; u < 4; ++u) {
        int x = (i0 + u < n) ? in[i0 + u] : 0;
        v[u] = tot;
        tot += x;
    }
    ls[threadIdx.x] = tot;
    __syncthreads();
    for (int off = 1; off < 256; off <<= 1) {
        int x = (threadIdx.x >= off) ? ls[threadIdx.x - off] : 0;
        __syncthreads();
        ls[threadIdx.x] += x;
        __syncthreads();
    }
    int texcl = ls[threadIdx.x] - tot;
#pragma unroll
    for (int u = 0; u < 4; ++u)
        if (i0 + u < n) out[i0 + u] = texcl + v[u];
    if (threadIdx.x == 255) part[blockIdx.x] = ls[255];
}

__global__ void scan2_kernel(int* __restrict__ part, int nb, int* __restrict__ out, int n)
{
    if (threadIdx.x == 0) {
        int acc = 0;
        for (int i = 0; i < nb; ++i) { int t = part[i]; part[i] = acc; acc += t; }
        out[n] = acc;
    }
}

__global__ __launch_bounds__(256) void scan3_kernel(
    int* __restrict__ out, const int* __restrict__ part, int n)
{
    int i = blockIdx.x * 256 + threadIdx.x;
    if (i < n) out[i] += part[blockIdx.x >> 2];
}

// CSR scatter: es[nstart[d]+rank[e]] = src | (type<<17)
__global__ __launch_bounds__(256) void scatter_kernel(
    const int* __restrict__ src, const int* __restrict__ dst, const int* __restrict__ et,
    const int* __restrict__ rank, const int* __restrict__ nstart,
    int* __restrict__ es, int E)
{
    int e = blockIdx.x * 256 + threadIdx.x;
    if (e < E)
        es[nstart[dst[e]] + rank[e]] = src[e] | (et[e] << 17);
}

// f32 -> bf16 convert (8 elems/thread)
__global__ __launch_bounds__(256) void tobf16_kernel(
    const float* __restrict__ in, unsigned short* __restrict__ out, int total8)
{
    int i = blockIdx.x * 256 + threadIdx.x;
    if (i >= total8) return;
    const float4* ip = (const float4*)(in + (size_t)i * 8);
    float4 a = ip[0], b = ip[1];
    uint4 o;
    o.x = pack2bf(a.x, a.y); o.y = pack2bf(a.z, a.w);
    o.z = pack2bf(b.x, b.y); o.w = pack2bf(b.z, b.w);
    *(uint4*)(out + (size_t)i * 8) = o;
}

// pre-permute W (32 relations) into MFMA A-fragment layout, bf16:
// wfrag[t][ks][jt][lane][8] = W[t][ks*32+(lane>>4)*8+jj][jt*16+(lane&15)]
template<int K>
__global__ __launch_bounds__(256) void wfrag_kernel(
    const float* __restrict__ W, unsigned short* __restrict__ wfrag)
{
    constexpr int KS = K / 32;
    int idx = blockIdx.x * 256 + threadIdx.x;
    int total = RNUM * KS * 4 * 64;
    if (idx >= total) return;
    int lane = idx & 63;
    int tmp = idx >> 6;
    int jt = tmp & 3; tmp >>= 2;
    int ks = tmp % KS;
    int t = tmp / KS;
    int col = jt * 16 + (lane & 15);
    int kb = ks * 32 + (lane >> 4) * 8;
    const float* Wp = W + ((size_t)t * K + kb) * HD + col;
    uint4 o;
    o.x = pack2bf(Wp[0 * HD], Wp[1 * HD]);
    o.y = pack2bf(Wp[2 * HD], Wp[3 * HD]);
    o.z = pack2bf(Wp[4 * HD], Wp[5 * HD]);
    o.w = pack2bf(Wp[6 * HD], Wp[7 * HD]);
    *(uint4*)(wfrag + (size_t)idx * 8) = o;
}

// dst-major gather-GEMM: block owns a 1024-row CSR window, counting-sorts its
// edges by type in LDS (int atomics only), runs 16-edge single-type MFMA
// batches, writes each message row once to its own C slot (no accumulation).
template<int K>
__global__ __launch_bounds__(256) void gemm_kernel(
    const unsigned short* __restrict__ xb, const int* __restrict__ es,
    const int* __restrict__ nstart, const unsigned short* __restrict__ wfrag,
    unsigned short* __restrict__ C, int n_lo, int n_hi, int cap)
{
    constexpr int KS = K / 32;
    __shared__ int s_es[WROWS];
    __shared__ unsigned short s_idx[WROWS];
    __shared__ int hist[RNUM], tbase[RNUM], tcur[RNUM];
    __shared__ int bdesc[WROWS / 16 + RNUM + 2];
    __shared__ int nb_s;
    const int tid = threadIdx.x;
    const int e_lo = nstart[n_lo];
    const int e_hi = nstart[n_hi];
    int rows = e_hi - e_lo;
    if (rows > cap) rows = cap;            // overflow clamp (never expected)
    const int r0 = blockIdx.x * WROWS;
    if (r0 >= rows) return;
    const int rcnt = (WROWS < rows - r0) ? WROWS : (rows - r0);

    for (int i = tid; i < rcnt; i += 256) s_es[i] = es[e_lo + r0 + i];
    if (tid < RNUM) hist[tid] = 0;
    __syncthreads();
    for (int i = tid; i < rcnt; i += 256)
        atomicAdd(&hist[(s_es[i] >> 17) & 31], 1);
    __syncthreads();
    if (tid == 0) {
        int acc = 0, nb = 0;
        for (int t = 0; t < RNUM; ++t) {
            tbase[t] = acc;
            for (int c2 = 0; c2 < hist[t]; c2 += 16)
                bdesc[nb++] = (t << 10) | (acc + c2);
            acc += hist[t];
        }
        nb_s = nb;
    }
    __syncthreads();
    if (tid < RNUM) tcur[tid] = tbase[tid];
    __syncthreads();
    for (int i = tid; i < rcnt; i += 256) {
        int t = (s_es[i] >> 17) & 31;
        int pos = atomicAdd(&tcur[t], 1);
        s_idx[pos] = (unsigned short)i;
    }
    __syncthreads();

    const int nb = nb_s;
    const int lane = tid & 63;
    const int wid = tid >> 6;
    const int b0 = (nb * wid) >> 2;        // contiguous range per wave -> W L1 reuse
    const int b1 = (nb * (wid + 1)) >> 2;
    for (int bi = b0; bi < b1; ++bi) {
        const int desc = bdesc[bi];
        const int t = desc >> 10;
        const int p0 = desc & 1023;
        const int tend = tbase[t] + hist[t];
        const int c = p0 + (lane & 15);
        const bool val = c < tend;
        const int idx = s_idx[val ? c : p0];
        const int src = s_es[idx] & 0x1FFFF;
        const unsigned short* wt = wfrag + (size_t)t * (KS * 2048);
        const unsigned short* xp = xb + (size_t)src * K + (lane >> 4) * 8;
        f32x4 acc[4];
#pragma unroll
        for (int jt = 0; jt < 4; ++jt) acc[jt] = (f32x4)0.0f;
#pragma unroll
        for (int ks = 0; ks < KS; ++ks) {
            bf16x8 bx = *(const bf16x8*)(xp + ks * 32);
#pragma unroll
            for (int jt = 0; jt < 4; ++jt) {
                bf16x8 aw = *(const bf16x8*)(wt + (size_t)((ks * 4 + jt) * 64 + lane) * 8);
                acc[jt] = __builtin_amdgcn_mfma_f32_16x16x32_bf16(aw, bx, acc[jt], 0, 0, 0);
            }
        }
        if (val) {
            unsigned short* cr = C + (size_t)(r0 + idx) * HD + (lane >> 4) * 4;
#pragma unroll
            for (int jt = 0; jt < 4; ++jt) {
                uint2 pk;
                pk.x = pack2bf(acc[jt][0], acc[jt][1]);
                pk.y = pack2bf(acc[jt][2], acc[jt][3]);
                *(uint2*)(cr + jt * 16) = pk;
            }
        }
    }
}

// streaming per-node reduce: type-inverse means from contiguous es, C rows
// streamed contiguously, root term x@Wroot computed in-kernel (f32), bias+relu.
template<int K>
__global__ __launch_bounds__(256) void reduce_kernel(
    const unsigned short* __restrict__ xb, const int* __restrict__ es,
    const int* __restrict__ nstart, const float* __restrict__ Root,
    const float* __restrict__ bias, unsigned short* __restrict__ hout,
    const unsigned short* __restrict__ C, int n_lo, int n_hi, int cap)
{
    __shared__ float sW[K * HD];
    __shared__ float sx[4][K];
    __shared__ int scnt[4][RNUM];
    __shared__ float sinv[4][RNUM];
    const int tid = threadIdx.x, lane = tid & 63, wid = tid >> 6;
    for (int i = tid; i < K * HD / 4; i += 256)
        ((float4*)sW)[i] = ((const float4*)Root)[i];
    const int e_lo = nstart[n_lo];
    const int node = n_lo + blockIdx.x * 4 + wid;
    const bool active = node < n_hi;
    int rs = 0, re = 0;
    if (active) { rs = nstart[node]; re = nstart[node + 1]; }
    if (lane < RNUM) scnt[wid][lane] = 0;
    if (active)
        for (int i = lane; i < K; i += 64) sx[wid][i] = b2f(xb[(size_t)node * K + i]);
    __syncthreads();
    for (int e = rs + lane; e < re; e += 64)
        atomicAdd(&scnt[wid][(es[e] >> 17) & 31], 1);
    __syncthreads();
    if (lane < RNUM) {
        int c = scnt[wid][lane];
        sinv[wid][lane] = 1.0f / (float)(c > 1 ? c : 1);
    }
    __syncthreads();
    float acc = bias[lane];
#pragma unroll 8
    for (int k = 0; k < K; ++k)
        acc = fmaf(sx[wid][k], sW[k * HD + lane], acc);
    for (int e = rs; e < re; ++e) {
        int row = e - e_lo;
        float iv = sinv[wid][(es[e] >> 17) & 31];
        if ((unsigned)row < (unsigned)cap)
            acc += iv * b2f(C[(size_t)row * HD + lane]);
    }
    if (active)
        hout[(size_t)node * HD + lane] = f2b(fmaxf(acc, 0.f));
}

// mean-pool h per graph; batch sorted -> register run accumulation
__global__ __launch_bounds__(256) void pool_kernel(
    const unsigned short* __restrict__ h, const int* __restrict__ batch,
    float* __restrict__ pool, float* __restrict__ gcnt, int col0, int n)
{
    const int lane = threadIdx.x & 63;
    const int wid = (blockIdx.x * 256 + threadIdx.x) >> 6;
    const int RANGE = 256;
    int n0 = wid * RANGE;
    if (n0 >= n) return;
    int n1 = n0 + RANGE;
    if (n1 > n) n1 = n;
    int cur = batch[n0];
    float acc = 0.f, c = 0.f;
    for (int i = n0; i < n1; ++i) {
        int b = batch[i];
        if (b != cur) {
            unsafeAtomicAdd(&pool[(size_t)cur * 128 + col0 + lane], acc);
            if (lane == 0) unsafeAtomicAdd(&gcnt[cur], c);
            acc = 0.f; c = 0.f; cur = b;
        }
        acc += b2f(h[(size_t)i * HD + lane]);
        c += 1.f;
    }
    unsafeAtomicAdd(&pool[(size_t)cur * 128 + col0 + lane], acc);
    if (lane == 0) unsafeAtomicAdd(&gcnt[cur], c);
}

__global__ __launch_bounds__(512) void depth_kernel(
    const float* __restrict__ depth, float* __restrict__ dnorm, int Bn)
{
    __shared__ float ls[8];
    __shared__ float smean, sstd;
    const int t = threadIdx.x, lane = t & 63, wv = t >> 6;
    float d = (t < Bn) ? depth[t] : 0.f;
    float s = d;
#pragma unroll
    for (int o = 32; o; o >>= 1) s += __shfl_down(s, o, 64);
    if (lane == 0) ls[wv] = s;
    __syncthreads();
    if (t == 0) {
        float tot = 0.f;
        for (int i = 0; i < 8; ++i) tot += ls[i];
        smean = tot / (float)Bn;
    }
    __syncthreads();
    float mean = smean;
    float df = (t < Bn) ? (d - mean) : 0.f;
    s = df * df;
#pragma unroll
    for (int o = 32; o; o >>= 1) s += __shfl_down(s, o, 64);
    __syncthreads();
    if (lane == 0) ls[wv] = s;
    __syncthreads();
    if (t == 0) {
        float tot = 0.f;
        for (int i = 0; i < 8; ++i) tot += ls[i];
        sstd = sqrtf(tot / (float)Bn);
    }
    __syncthreads();
    if (t < Bn) dnorm[t] = df / (sstd + 1e-6f);
}

__global__ __launch_bounds__(256) void regress_kernel(
    const float* __restrict__ pool, const float* __restrict__ gcnt_s,
    const float* __restrict__ gcnt_g, const float* __restrict__ dnorm,
    const float* __restrict__ rW1, const float* __restrict__ rB1,
    const float* __restrict__ rW2, const float* __restrict__ rB2,
    float* __restrict__ pred, int Bn)
{
    const int lane = threadIdx.x & 63;
    const int g = (blockIdx.x * 256 + threadIdx.x) >> 6;
    if (g >= Bn) return;
    const float is = 1.f / fmaxf(gcnt_s[g], 1.f);
    const float ig = 1.f / fmaxf(gcnt_g[g], 1.f);
    const float* pr = pool + (size_t)g * 128;
    float acc = rB1[lane];
    for (int k = 0; k < 64; ++k)
        acc = fmaf(pr[k] * is, rW1[k * 64 + lane], acc);
    for (int k = 64; k < 128; ++k)
        acc = fmaf(pr[k] * ig, rW1[k * 64 + lane], acc);
    acc = fmaf(dnorm[g], rW1[128 * 64 + lane], acc);
    float v = fmaxf(acc, 0.f) * rW2[lane];
#pragma unroll
    for (int o = 32; o; o >>= 1) v += __shfl_down(v, o, 64);
    if (lane == 0) pred[g] = v + rB2[0];
}

// ---------------- launch ----------------

extern "C" void kernel_launch(void* const* d_in, const int* in_sizes, int n_in,
                              void* d_out, int out_size, void* d_ws, size_t ws_size,
                              hipStream_t stream)
{
    const int E1 = in_sizes[2];
    const int E2 = in_sizes[6];
    const int Emax = E1 > E2 ? E1 : E2;
    const int N = in_sizes[3];
    const int IN = in_sizes[0] / N;   // 128
    const int Bn = in_sizes[8];

    const float* state_x = (const float*)d_in[0];
    const int* s_ei = (const int*)d_in[1];
    const int* s_et = (const int*)d_in[2];
    const int* s_batch = (const int*)d_in[3];
    const float* goal_x = (const float*)d_in[4];
    const int* g_ei = (const int*)d_in[5];
    const int* g_et = (const int*)d_in[6];
    const int* g_batch = (const int*)d_in[7];
    const float* depth = (const float*)d_in[8];
    const float* sW1 = (const float*)d_in[9];
    const float* sRoot1 = (const float*)d_in[10];
    const float* sB1 = (const float*)d_in[11];
    const float* sW2 = (const float*)d_in[12];
    const float* sRoot2 = (const float*)d_in[13];
    const float* sB2 = (const float*)d_in[14];
    const float* gW1 = (const float*)d_in[15];
    const float* gRoot1 = (const float*)d_in[16];
    const float* gB1 = (const float*)d_in[17];
    const float* gW2 = (const float*)d_in[18];
    const float* gRoot2 = (const float*)d_in[19];
    const float* gB2 = (const float*)d_in[20];
    const float* rW1 = (const float*)d_in[21];
    const float* rB1 = (const float*)d_in[22];
    const float* rW2 = (const float*)d_in[23];
    const float* rB2 = (const float*)d_in[24];
    float* pred = (float*)d_out;

    const int nbScan = (N + 1023) / 1024;

    // fixed workspace budget
    size_t fixedb = 0;
    fixedb += WS_ALIGN((size_t)N * 4);              // deg
    fixedb += WS_ALIGN((size_t)(N + 1) * 4);        // nstart
    fixedb += WS_ALIGN((size_t)Emax * 4);           // rank
    fixedb += WS_ALIGN((size_t)nbScan * 4);         // part
    fixedb += WS_ALIGN((size_t)Emax * 4);           // es
    fixedb += WS_ALIGN((size_t)N * IN * 2);         // xb
    fixedb += WS_ALIGN((size_t)N * HD * 2);         // h1
    fixedb += WS_ALIGN((size_t)N * HD * 2);         // h2
    fixedb += WS_ALIGN((size_t)RNUM * 4 * 4 * 64 * 8 * 2);  // wf1
    fixedb += WS_ALIGN((size_t)RNUM * 2 * 4 * 64 * 8 * 2);  // wf2
    fixedb += WS_ALIGN((size_t)Bn * 128 * 4);       // pool
    fixedb += 3 * WS_ALIGN((size_t)Bn * 4);         // gcnt_s, gcnt_g, dnorm

    size_t avail = (ws_size > fixedb + (size_t)(32 << 20))
                 ? ws_size - fixedb - (size_t)(32 << 20) : (size_t)(32 << 20);
    size_t capRows = avail / ((size_t)HD * 2);
    if (capRows > (size_t)Emax) capRows = (size_t)Emax;
    int nchunk = 1;
    if ((size_t)Emax > capRows) {
        nchunk = 2;
        while ((size_t)((double)Emax * 1.4 / nchunk) > capRows && nchunk < 256) nchunk++;
    }
    const int npc = (N + nchunk - 1) / nchunk;
    const int CAP = (int)capRows;
    const int gB = (int)((capRows + WROWS - 1) / WROWS);
    const int rB = (npc + 3) / 4;

    char* p = (char*)d_ws;
    auto alloc = [&](size_t bytes) { char* r = p; p += WS_ALIGN(bytes); return r; };
    int* deg    = (int*)alloc((size_t)N * 4);
    int* nstart = (int*)alloc((size_t)(N + 1) * 4);
    int* rank   = (int*)alloc((size_t)Emax * 4);
    int* part   = (int*)alloc((size_t)nbScan * 4);
    int* es     = (int*)alloc((size_t)Emax * 4);
    unsigned short* xb  = (unsigned short*)alloc((size_t)N * IN * 2);
    unsigned short* h1  = (unsigned short*)alloc((size_t)N * HD * 2);
    unsigned short* h2  = (unsigned short*)alloc((size_t)N * HD * 2);
    unsigned short* wf1 = (unsigned short*)alloc((size_t)RNUM * 4 * 4 * 64 * 8 * 2);
    unsigned short* wf2 = (unsigned short*)alloc((size_t)RNUM * 2 * 4 * 64 * 8 * 2);
    float* pool   = (float*)alloc((size_t)Bn * 128 * 4);
    float* gcnt_s = (float*)alloc((size_t)Bn * 4);
    float* gcnt_g = (float*)alloc((size_t)Bn * 4);
    float* dnorm  = (float*)alloc((size_t)Bn * 4);
    unsigned short* C = (unsigned short*)alloc(capRows * (size_t)HD * 2);

    hipMemsetAsync(pool, 0, (size_t)Bn * 128 * 4, stream);
    hipMemsetAsync(gcnt_s, 0, (size_t)Bn * 4, stream);
    hipMemsetAsync(gcnt_g, 0, (size_t)Bn * 4, stream);

    for (int enc = 0; enc < 2; ++enc) {
        const float* x = enc ? goal_x : state_x;
        const int* ei = enc ? g_ei : s_ei;
        const int* et = enc ? g_et : s_et;
        const int* batch = enc ? g_batch : s_batch;
        const float* W1 = enc ? gW1 : sW1;
        const float* Root1 = enc ? gRoot1 : sRoot1;
        const float* B1 = enc ? gB1 : sB1;
        const float* W2 = enc ? gW2 : sW2;
        const float* Root2 = enc ? gRoot2 : sRoot2;
        const float* B2 = enc ? gB2 : sB2;
        float* gcnt = enc ? gcnt_g : gcnt_s;
        const int E = enc ? E2 : E1;
        const int* srcp = ei;
        const int* dstp = ei + E;
        const int ebl = (E + 255) / 256;

        hipMemsetAsync(deg, 0, (size_t)N * 4, stream);

        count_kernel<<<ebl, 256, 0, stream>>>(dstp, deg, rank, E);
        scan1_kernel<<<nbScan, 256, 0, stream>>>(deg, nstart, part, N);
        scan2_kernel<<<1, 64, 0, stream>>>(part, nbScan, nstart, N);
        scan3_kernel<<<nbScan * 4, 256, 0, stream>>>(nstart, part, N);
        scatter_kernel<<<ebl, 256, 0, stream>>>(srcp, dstp, et, rank, nstart, es, E);

        tobf16_kernel<<<(N * IN / 8 + 255) / 256, 256, 0, stream>>>(x, xb, N * IN / 8);
        wfrag_kernel<128><<<(RNUM * 4 * 4 * 64 + 255) / 256, 256, 0, stream>>>(W1, wf1);
        wfrag_kernel<64><<<(RNUM * 2 * 4 * 64 + 255) / 256, 256, 0, stream>>>(W2, wf2);

        // layer 1
        for (int c = 0; c < nchunk; ++c) {
            int n_lo = c * npc;
            int n_hi = n_lo + npc; if (n_hi > N) n_hi = N;
            if (n_lo >= n_hi) break;
            gemm_kernel<128><<<gB, 256, 0, stream>>>(xb, es, nstart, wf1, C, n_lo, n_hi, CAP);
            reduce_kernel<128><<<rB, 256, 0, stream>>>(xb, es, nstart, Root1, B1, h1, C, n_lo, n_hi, CAP);
        }
        // layer 2
        for (int c = 0; c < nchunk; ++c) {
            int n_lo = c * npc;
            int n_hi = n_lo + npc; if (n_hi > N) n_hi = N;
            if (n_lo >= n_hi) break;
            gemm_kernel<64><<<gB, 256, 0, stream>>>(h1, es, nstart, wf2, C, n_lo, n_hi, CAP);
            reduce_kernel<64><<<rB, 256, 0, stream>>>(h1, es, nstart, Root2, B2, h2, C, n_lo, n_hi, CAP);
        }
        // pool
        int pwaves = (N + 255) / 256;
        pool_kernel<<<(pwaves * 64 + 255) / 256, 256, 0, stream>>>(
            h2, batch, pool, gcnt, enc * 64, N);
    }

    depth_kernel<<<1, 512, 0, stream>>>(depth, dnorm, Bn);
    regress_kernel<<<(Bn * 64 + 255) / 256, 256, 0, stream>>>(
        pool, gcnt_s, gcnt_g, dnorm, rW1, rB1, rW2, rB2, pred, Bn);
}

// Round 7
// 1768.937 us; speedup vs baseline: 2.3869x; 1.2181x over previous
//
#include <hip/hip_runtime.h>

// N=100000 nodes, E=1600000 edges, IN=128, H=64, R=32, B=512
constexpr int HD    = 64;
constexpr int RNUM  = 32;
constexpr int WROWS = 1024;   // CSR rows per gemm block

typedef __attribute__((ext_vector_type(4))) float f32x4;
typedef __attribute__((ext_vector_type(8))) short bf16x8;

#define WS_ALIGN(x) (((x) + size_t(255)) & ~size_t(255))

__device__ inline float b2f(unsigned short u) {
    return __uint_as_float(((unsigned)u) << 16);
}
__device__ inline unsigned short f2b(float f) {
    unsigned u = __float_as_uint(f);
    u = (u + 0x7FFF + ((u >> 16) & 1)) >> 16;
    return (unsigned short)u;
}
__device__ inline unsigned pack2bf(float a, float b) {
    return (unsigned)f2b(a) | ((unsigned)f2b(b) << 16);
}

// ---------------- preprocessing ----------------

__global__ __launch_bounds__(256) void count_kernel(
    const int* __restrict__ dst, int* __restrict__ deg, int* __restrict__ rank, int E)
{
    int e = blockIdx.x * 256 + threadIdx.x;
    if (e < E) rank[e] = atomicAdd(&deg[dst[e]], 1);
}

__global__ __launch_bounds__(256) void scan1_kernel(
    const int* __restrict__ in, int* __restrict__ out, int* __restrict__ part, int n)
{
    __shared__ int ls[256];
    const int i0 = blockIdx.x * 1024 + threadIdx.x * 4;
    int v[4];
    int tot = 0;
#pragma unroll
    for (int u = 0; u < 4; ++u) {
        int x = (i0 + u < n) ? in[i0 + u] : 0;
        v[u] = tot;
        tot += x;
    }
    ls[threadIdx.x] = tot;
    __syncthreads();
    for (int off = 1; off < 256; off <<= 1) {
        int x = (threadIdx.x >= off) ? ls[threadIdx.x - off] : 0;
        __syncthreads();
        ls[threadIdx.x] += x;
        __syncthreads();
    }
    int texcl = ls[threadIdx.x] - tot;
#pragma unroll
    for (int u = 0; u < 4; ++u)
        if (i0 + u < n) out[i0 + u] = texcl + v[u];
    if (threadIdx.x == 255) part[blockIdx.x] = ls[255];
}

__global__ void scan2_kernel(int* __restrict__ part, int nb, int* __restrict__ out, int n)
{
    if (threadIdx.x == 0) {
        int acc = 0;
        for (int i = 0; i < nb; ++i) { int t = part[i]; part[i] = acc; acc += t; }
        out[n] = acc;
    }
}

__global__ __launch_bounds__(256) void scan3_kernel(
    int* __restrict__ out, const int* __restrict__ part, int n)
{
    int i = blockIdx.x * 256 + threadIdx.x;
    if (i < n) out[i] += part[blockIdx.x >> 2];
}

// CSR scatter: es[nstart[d]+rank[e]] = src | (type<<17)
__global__ __launch_bounds__(256) void scatter_kernel(
    const int* __restrict__ src, const int* __restrict__ dst, const int* __restrict__ et,
    const int* __restrict__ rank, const int* __restrict__ nstart,
    int* __restrict__ es, int E)
{
    int e = blockIdx.x * 256 + threadIdx.x;
    if (e < E)
        es[nstart[dst[e]] + rank[e]] = src[e] | (et[e] << 17);
}

__global__ __launch_bounds__(256) void tobf16_kernel(
    const float* __restrict__ in, unsigned short* __restrict__ out, int total8)
{
    int i = blockIdx.x * 256 + threadIdx.x;
    if (i >= total8) return;
    const float4* ip = (const float4*)(in + (size_t)i * 8);
    float4 a = ip[0], b = ip[1];
    uint4 o;
    o.x = pack2bf(a.x, a.y); o.y = pack2bf(a.z, a.w);
    o.z = pack2bf(b.x, b.y); o.w = pack2bf(b.z, b.w);
    *(uint4*)(out + (size_t)i * 8) = o;
}

// pre-permute W (32 relations) into MFMA A-fragment layout, bf16
template<int K>
__global__ __launch_bounds__(256) void wfrag_kernel(
    const float* __restrict__ W, unsigned short* __restrict__ wfrag)
{
    constexpr int KS = K / 32;
    int idx = blockIdx.x * 256 + threadIdx.x;
    int total = RNUM * KS * 4 * 64;
    if (idx >= total) return;
    int lane = idx & 63;
    int tmp = idx >> 6;
    int jt = tmp & 3; tmp >>= 2;
    int ks = tmp % KS;
    int t = tmp / KS;
    int col = jt * 16 + (lane & 15);
    int kb = ks * 32 + (lane >> 4) * 8;
    const float* Wp = W + ((size_t)t * K + kb) * HD + col;
    uint4 o;
    o.x = pack2bf(Wp[0 * HD], Wp[1 * HD]);
    o.y = pack2bf(Wp[2 * HD], Wp[3 * HD]);
    o.z = pack2bf(Wp[4 * HD], Wp[5 * HD]);
    o.w = pack2bf(Wp[6 * HD], Wp[7 * HD]);
    *(uint4*)(wfrag + (size_t)idx * 8) = o;
}

// same fragment permute for a single matrix (Wroot)
template<int K>
__global__ __launch_bounds__(256) void wfroot_kernel(
    const float* __restrict__ Root, unsigned short* __restrict__ wfr)
{
    constexpr int KS = K / 32;
    int idx = blockIdx.x * 256 + threadIdx.x;
    int total = KS * 4 * 64;
    if (idx >= total) return;
    int lane = idx & 63;
    int tmp = idx >> 6;
    int jt = tmp & 3;
    int ks = tmp >> 2;
    int col = jt * 16 + (lane & 15);
    int kb = ks * 32 + (lane >> 4) * 8;
    const float* Wp = Root + (size_t)kb * HD + col;
    uint4 o;
    o.x = pack2bf(Wp[0 * HD], Wp[1 * HD]);
    o.y = pack2bf(Wp[2 * HD], Wp[3 * HD]);
    o.z = pack2bf(Wp[4 * HD], Wp[5 * HD]);
    o.w = pack2bf(Wp[6 * HD], Wp[7 * HD]);
    *(uint4*)(wfr + (size_t)idx * 8) = o;
}

// dense MFMA GEMM: hroot[n][j] = bias[j] + sum_k x[n][k]*Root[k][j]  (bf16 out)
template<int K>
__global__ __launch_bounds__(256) void rootmm_kernel(
    const unsigned short* __restrict__ xb, const unsigned short* __restrict__ wfr,
    const float* __restrict__ bias, unsigned short* __restrict__ hroot, int N)
{
    constexpr int KS = K / 32;
    __shared__ unsigned short sW[KS * 4 * 64 * 8];
    __shared__ float sbias[HD];
    const int tid = threadIdx.x;
    for (int i = tid; i < KS * 256; i += 256)
        ((uint4*)sW)[i] = ((const uint4*)wfr)[i];
    if (tid < HD) sbias[tid] = bias[tid];
    __syncthreads();
    const int lane = tid & 63;
    const int wid = tid >> 6;
    const int jb = (lane >> 4) * 4;
#pragma unroll
    for (int b = 0; b < 4; ++b) {
        const int node0 = blockIdx.x * 256 + wid * 64 + b * 16;
        const int node = node0 + (lane & 15);
        const int nclamp = node < N ? node : N - 1;
        const unsigned short* xp = xb + (size_t)nclamp * K + (lane >> 4) * 8;
        f32x4 acc[4];
#pragma unroll
        for (int jt = 0; jt < 4; ++jt) acc[jt] = (f32x4)0.0f;
#pragma unroll
        for (int ks = 0; ks < KS; ++ks) {
            bf16x8 bx = *(const bf16x8*)(xp + ks * 32);
#pragma unroll
            for (int jt = 0; jt < 4; ++jt) {
                bf16x8 aw = *(const bf16x8*)(sW + (size_t)((ks * 4 + jt) * 64 + lane) * 8);
                acc[jt] = __builtin_amdgcn_mfma_f32_16x16x32_bf16(aw, bx, acc[jt], 0, 0, 0);
            }
        }
        if (node < N) {
            unsigned short* hr = hroot + (size_t)node * HD + jb;
#pragma unroll
            for (int jt = 0; jt < 4; ++jt) {
                const int j0 = jt * 16 + jb;
                uint2 pk;
                pk.x = pack2bf(acc[jt][0] + sbias[j0 + 0], acc[jt][1] + sbias[j0 + 1]);
                pk.y = pack2bf(acc[jt][2] + sbias[j0 + 2], acc[jt][3] + sbias[j0 + 3]);
                *(uint2*)(hr + jt * 16) = pk;
            }
        }
    }
}

// dst-major gather-GEMM (unchanged from round 6)
template<int K>
__global__ __launch_bounds__(256) void gemm_kernel(
    const unsigned short* __restrict__ xb, const int* __restrict__ es,
    const int* __restrict__ nstart, const unsigned short* __restrict__ wfrag,
    unsigned short* __restrict__ C, int n_lo, int n_hi, int cap)
{
    constexpr int KS = K / 32;
    __shared__ int s_es[WROWS];
    __shared__ unsigned short s_idx[WROWS];
    __shared__ int hist[RNUM], tbase[RNUM], tcur[RNUM];
    __shared__ int bdesc[WROWS / 16 + RNUM + 2];
    __shared__ int nb_s;
    const int tid = threadIdx.x;
    const int e_lo = nstart[n_lo];
    const int e_hi = nstart[n_hi];
    int rows = e_hi - e_lo;
    if (rows > cap) rows = cap;
    const int r0 = blockIdx.x * WROWS;
    if (r0 >= rows) return;
    const int rcnt = (WROWS < rows - r0) ? WROWS : (rows - r0);

    for (int i = tid; i < rcnt; i += 256) s_es[i] = es[e_lo + r0 + i];
    if (tid < RNUM) hist[tid] = 0;
    __syncthreads();
    for (int i = tid; i < rcnt; i += 256)
        atomicAdd(&hist[(s_es[i] >> 17) & 31], 1);
    __syncthreads();
    if (tid == 0) {
        int acc = 0, nb = 0;
        for (int t = 0; t < RNUM; ++t) {
            tbase[t] = acc;
            for (int c2 = 0; c2 < hist[t]; c2 += 16)
                bdesc[nb++] = (t << 10) | (acc + c2);
            acc += hist[t];
        }
        nb_s = nb;
    }
    __syncthreads();
    if (tid < RNUM) tcur[tid] = tbase[tid];
    __syncthreads();
    for (int i = tid; i < rcnt; i += 256) {
        int t = (s_es[i] >> 17) & 31;
        int pos = atomicAdd(&tcur[t], 1);
        s_idx[pos] = (unsigned short)i;
    }
    __syncthreads();

    const int nb = nb_s;
    const int lane = tid & 63;
    const int wid = tid >> 6;
    const int b0 = (nb * wid) >> 2;
    const int b1 = (nb * (wid + 1)) >> 2;
    for (int bi = b0; bi < b1; ++bi) {
        const int desc = bdesc[bi];
        const int t = desc >> 10;
        const int p0 = desc & 1023;
        const int tend = tbase[t] + hist[t];
        const int c = p0 + (lane & 15);
        const bool val = c < tend;
        const int idx = s_idx[val ? c : p0];
        const int src = s_es[idx] & 0x1FFFF;
        const unsigned short* wt = wfrag + (size_t)t * (KS * 2048);
        const unsigned short* xp = xb + (size_t)src * K + (lane >> 4) * 8;
        f32x4 acc[4];
#pragma unroll
        for (int jt = 0; jt < 4; ++jt) acc[jt] = (f32x4)0.0f;
#pragma unroll
        for (int ks = 0; ks < KS; ++ks) {
            bf16x8 bx = *(const bf16x8*)(xp + ks * 32);
#pragma unroll
            for (int jt = 0; jt < 4; ++jt) {
                bf16x8 aw = *(const bf16x8*)(wt + (size_t)((ks * 4 + jt) * 64 + lane) * 8);
                acc[jt] = __builtin_amdgcn_mfma_f32_16x16x32_bf16(aw, bx, acc[jt], 0, 0, 0);
            }
        }
        if (val) {
            unsigned short* cr = C + (size_t)(r0 + idx) * HD + (lane >> 4) * 4;
#pragma unroll
            for (int jt = 0; jt < 4; ++jt) {
                uint2 pk;
                pk.x = pack2bf(acc[jt][0], acc[jt][1]);
                pk.y = pack2bf(acc[jt][2], acc[jt][3]);
                *(uint2*)(cr + jt * 16) = pk;
            }
        }
    }
}

// streaming per-node reduce: hroot + per-type means of C rows; relu -> bf16
__global__ __launch_bounds__(256) void reduce_kernel(
    const int* __restrict__ es, const int* __restrict__ nstart,
    const unsigned short* __restrict__ hroot, unsigned short* __restrict__ hout,
    const unsigned short* __restrict__ C, int n_lo, int n_hi, int cap)
{
    __shared__ int scnt[4][RNUM];
    __shared__ float sinv[4][RNUM];
    const int tid = threadIdx.x, lane = tid & 63, wid = tid >> 6;
    const int e_lo = nstart[n_lo];
    const int node = n_lo + blockIdx.x * 4 + wid;
    const bool active = node < n_hi;
    int rs = 0, re = 0;
    if (active) { rs = nstart[node]; re = nstart[node + 1]; }
    if (lane < RNUM) scnt[wid][lane] = 0;
    __syncthreads();
    for (int e = rs + lane; e < re; e += 64)
        atomicAdd(&scnt[wid][(es[e] >> 17) & 31], 1);
    __syncthreads();
    if (lane < RNUM) {
        int c = scnt[wid][lane];
        sinv[wid][lane] = 1.0f / (float)(c > 1 ? c : 1);
    }
    __syncthreads();
    if (!active) return;
    float acc = b2f(hroot[(size_t)node * HD + lane]);
    for (int e = rs; e < re; ++e) {
        int row = e - e_lo;
        float iv = sinv[wid][(es[e] >> 17) & 31];
        if ((unsigned)row < (unsigned)cap)
            acc += iv * b2f(C[(size_t)row * HD + lane]);
    }
    hout[(size_t)node * HD + lane] = f2b(fmaxf(acc, 0.f));
}

// mean-pool h per graph; batch sorted -> register run accumulation
__global__ __launch_bounds__(256) void pool_kernel(
    const unsigned short* __restrict__ h, const int* __restrict__ batch,
    float* __restrict__ pool, float* __restrict__ gcnt, int col0, int n)
{
    const int lane = threadIdx.x & 63;
    const int wid = (blockIdx.x * 256 + threadIdx.x) >> 6;
    const int RANGE = 256;
    int n0 = wid * RANGE;
    if (n0 >= n) return;
    int n1 = n0 + RANGE;
    if (n1 > n) n1 = n;
    int cur = batch[n0];
    float acc = 0.f, c = 0.f;
    for (int i = n0; i < n1; ++i) {
        int b = batch[i];
        if (b != cur) {
            unsafeAtomicAdd(&pool[(size_t)cur * 128 + col0 + lane], acc);
            if (lane == 0) unsafeAtomicAdd(&gcnt[cur], c);
            acc = 0.f; c = 0.f; cur = b;
        }
        acc += b2f(h[(size_t)i * HD + lane]);
        c += 1.f;
    }
    unsafeAtomicAdd(&pool[(size_t)cur * 128 + col0 + lane], acc);
    if (lane == 0) unsafeAtomicAdd(&gcnt[cur], c);
}

__global__ __launch_bounds__(512) void depth_kernel(
    const float* __restrict__ depth, float* __restrict__ dnorm, int Bn)
{
    __shared__ float ls[8];
    __shared__ float smean, sstd;
    const int t = threadIdx.x, lane = t & 63, wv = t >> 6;
    float d = (t < Bn) ? depth[t] : 0.f;
    float s = d;
#pragma unroll
    for (int o = 32; o; o >>= 1) s += __shfl_down(s, o, 64);
    if (lane == 0) ls[wv] = s;
    __syncthreads();
    if (t == 0) {
        float tot = 0.f;
        for (int i = 0; i < 8; ++i) tot += ls[i];
        smean = tot / (float)Bn;
    }
    __syncthreads();
    float mean = smean;
    float df = (t < Bn) ? (d - mean) : 0.f;
    s = df * df;
#pragma unroll
    for (int o = 32; o; o >>= 1) s += __shfl_down(s, o, 64);
    __syncthreads();
    if (lane == 0) ls[wv] = s;
    __syncthreads();
    if (t == 0) {
        float tot = 0.f;
        for (int i = 0; i < 8; ++i) tot += ls[i];
        sstd = sqrtf(tot / (float)Bn);
    }
    __syncthreads();
    if (t < Bn) dnorm[t] = df / (sstd + 1e-6f);
}

__global__ __launch_bounds__(256) void regress_kernel(
    const float* __restrict__ pool, const float* __restrict__ gcnt_s,
    const float* __restrict__ gcnt_g, const float* __restrict__ dnorm,
    const float* __restrict__ rW1, const float* __restrict__ rB1,
    const float* __restrict__ rW2, const float* __restrict__ rB2,
    float* __restrict__ pred, int Bn)
{
    const int lane = threadIdx.x & 63;
    const int g = (blockIdx.x * 256 + threadIdx.x) >> 6;
    if (g >= Bn) return;
    const float is = 1.f / fmaxf(gcnt_s[g], 1.f);
    const float ig = 1.f / fmaxf(gcnt_g[g], 1.f);
    const float* pr = pool + (size_t)g * 128;
    float acc = rB1[lane];
    for (int k = 0; k < 64; ++k)
        acc = fmaf(pr[k] * is, rW1[k * 64 + lane], acc);
    for (int k = 64; k < 128; ++k)
        acc = fmaf(pr[k] * ig, rW1[k * 64 + lane], acc);
    acc = fmaf(dnorm[g], rW1[128 * 64 + lane], acc);
    float v = fmaxf(acc, 0.f) * rW2[lane];
#pragma unroll
    for (int o = 32; o; o >>= 1) v += __shfl_down(v, o, 64);
    if (lane == 0) pred[g] = v + rB2[0];
}

// ---------------- launch ----------------

extern "C" void kernel_launch(void* const* d_in, const int* in_sizes, int n_in,
                              void* d_out, int out_size, void* d_ws, size_t ws_size,
                              hipStream_t stream)
{
    const int E1 = in_sizes[2];
    const int E2 = in_sizes[6];
    const int Emax = E1 > E2 ? E1 : E2;
    const int N = in_sizes[3];
    const int IN = in_sizes[0] / N;   // 128
    const int Bn = in_sizes[8];

    const float* state_x = (const float*)d_in[0];
    const int* s_ei = (const int*)d_in[1];
    const int* s_et = (const int*)d_in[2];
    const int* s_batch = (const int*)d_in[3];
    const float* goal_x = (const float*)d_in[4];
    const int* g_ei = (const int*)d_in[5];
    const int* g_et = (const int*)d_in[6];
    const int* g_batch = (const int*)d_in[7];
    const float* depth = (const float*)d_in[8];
    const float* sW1 = (const float*)d_in[9];
    const float* sRoot1 = (const float*)d_in[10];
    const float* sB1 = (const float*)d_in[11];
    const float* sW2 = (const float*)d_in[12];
    const float* sRoot2 = (const float*)d_in[13];
    const float* sB2 = (const float*)d_in[14];
    const float* gW1 = (const float*)d_in[15];
    const float* gRoot1 = (const float*)d_in[16];
    const float* gB1 = (const float*)d_in[17];
    const float* gW2 = (const float*)d_in[18];
    const float* gRoot2 = (const float*)d_in[19];
    const float* gB2 = (const float*)d_in[20];
    const float* rW1 = (const float*)d_in[21];
    const float* rB1 = (const float*)d_in[22];
    const float* rW2 = (const float*)d_in[23];
    const float* rB2 = (const float*)d_in[24];
    float* pred = (float*)d_out;

    const int nbScan = (N + 1023) / 1024;

    // fixed workspace budget
    size_t fixedb = 0;
    fixedb += WS_ALIGN((size_t)N * 4);              // deg
    fixedb += WS_ALIGN((size_t)(N + 1) * 4);        // nstart
    fixedb += WS_ALIGN((size_t)Emax * 4);           // rank
    fixedb += WS_ALIGN((size_t)nbScan * 4);         // part
    fixedb += WS_ALIGN((size_t)Emax * 4);           // es
    fixedb += WS_ALIGN((size_t)N * IN * 2);         // xb
    fixedb += WS_ALIGN((size_t)N * HD * 2);         // h1
    fixedb += WS_ALIGN((size_t)N * HD * 2);         // h2
    fixedb += WS_ALIGN((size_t)N * HD * 2);         // hroot
    fixedb += WS_ALIGN((size_t)RNUM * 4 * 4 * 64 * 8 * 2);  // wf1
    fixedb += WS_ALIGN((size_t)RNUM * 2 * 4 * 64 * 8 * 2);  // wf2
    fixedb += WS_ALIGN((size_t)4 * 4 * 64 * 8 * 2); // wfr1
    fixedb += WS_ALIGN((size_t)2 * 4 * 64 * 8 * 2); // wfr2
    fixedb += WS_ALIGN((size_t)Bn * 128 * 4);       // pool
    fixedb += 3 * WS_ALIGN((size_t)Bn * 4);         // gcnt_s, gcnt_g, dnorm

    size_t avail = (ws_size > fixedb + (size_t)(32 << 20))
                 ? ws_size - fixedb - (size_t)(32 << 20) : (size_t)(32 << 20);
    size_t capRows = avail / ((size_t)HD * 2);
    if (capRows > (size_t)Emax) capRows = (size_t)Emax;
    int nchunk = 1;
    if ((size_t)Emax > capRows) {
        nchunk = 2;
        while ((size_t)((double)Emax * 1.4 / nchunk) > capRows && nchunk < 256) nchunk++;
    }
    const int npc = (N + nchunk - 1) / nchunk;
    const int CAP = (int)capRows;
    const int gB = (int)((capRows + WROWS - 1) / WROWS);
    const int rB = (npc + 3) / 4;

    char* p = (char*)d_ws;
    auto alloc = [&](size_t bytes) { char* r = p; p += WS_ALIGN(bytes); return r; };
    int* deg    = (int*)alloc((size_t)N * 4);
    int* nstart = (int*)alloc((size_t)(N + 1) * 4);
    int* rank   = (int*)alloc((size_t)Emax * 4);
    int* part   = (int*)alloc((size_t)nbScan * 4);
    int* es     = (int*)alloc((size_t)Emax * 4);
    unsigned short* xb    = (unsigned short*)alloc((size_t)N * IN * 2);
    unsigned short* h1    = (unsigned short*)alloc((size_t)N * HD * 2);
    unsigned short* h2    = (unsigned short*)alloc((size_t)N * HD * 2);
    unsigned short* hroot = (unsigned short*)alloc((size_t)N * HD * 2);
    unsigned short* wf1   = (unsigned short*)alloc((size_t)RNUM * 4 * 4 * 64 * 8 * 2);
    unsigned short* wf2   = (unsigned short*)alloc((size_t)RNUM * 2 * 4 * 64 * 8 * 2);
    unsigned short* wfr1  = (unsigned short*)alloc((size_t)4 * 4 * 64 * 8 * 2);
    unsigned short* wfr2  = (unsigned short*)alloc((size_t)2 * 4 * 64 * 8 * 2);
    float* pool   = (float*)alloc((size_t)Bn * 128 * 4);
    float* gcnt_s = (float*)alloc((size_t)Bn * 4);
    float* gcnt_g = (float*)alloc((size_t)Bn * 4);
    float* dnorm  = (float*)alloc((size_t)Bn * 4);
    unsigned short* C = (unsigned short*)alloc(capRows * (size_t)HD * 2);

    hipMemsetAsync(pool, 0, (size_t)Bn * 128 * 4, stream);
    hipMemsetAsync(gcnt_s, 0, (size_t)Bn * 4, stream);
    hipMemsetAsync(gcnt_g, 0, (size_t)Bn * 4, stream);

    const int nmmB = (N + 255) / 256;

    for (int enc = 0; enc < 2; ++enc) {
        const float* x = enc ? goal_x : state_x;
        const int* ei = enc ? g_ei : s_ei;
        const int* et = enc ? g_et : s_et;
        const int* batch = enc ? g_batch : s_batch;
        const float* W1 = enc ? gW1 : sW1;
        const float* Root1 = enc ? gRoot1 : sRoot1;
        const float* B1 = enc ? gB1 : sB1;
        const float* W2 = enc ? gW2 : sW2;
        const float* Root2 = enc ? gRoot2 : sRoot2;
        const float* B2 = enc ? gB2 : sB2;
        float* gcnt = enc ? gcnt_g : gcnt_s;
        const int E = enc ? E2 : E1;
        const int* srcp = ei;
        const int* dstp = ei + E;
        const int ebl = (E + 255) / 256;

        hipMemsetAsync(deg, 0, (size_t)N * 4, stream);

        count_kernel<<<ebl, 256, 0, stream>>>(dstp, deg, rank, E);
        scan1_kernel<<<nbScan, 256, 0, stream>>>(deg, nstart, part, N);
        scan2_kernel<<<1, 64, 0, stream>>>(part, nbScan, nstart, N);
        scan3_kernel<<<nbScan * 4, 256, 0, stream>>>(nstart, part, N);
        scatter_kernel<<<ebl, 256, 0, stream>>>(srcp, dstp, et, rank, nstart, es, E);

        tobf16_kernel<<<(N * IN / 8 + 255) / 256, 256, 0, stream>>>(x, xb, N * IN / 8);
        wfrag_kernel<128><<<(RNUM * 4 * 4 * 64 + 255) / 256, 256, 0, stream>>>(W1, wf1);
        wfrag_kernel<64><<<(RNUM * 2 * 4 * 64 + 255) / 256, 256, 0, stream>>>(W2, wf2);
        wfroot_kernel<128><<<(4 * 4 * 64 + 255) / 256, 256, 0, stream>>>(Root1, wfr1);
        wfroot_kernel<64><<<(2 * 4 * 64 + 255) / 256, 256, 0, stream>>>(Root2, wfr2);

        // layer 1
        rootmm_kernel<128><<<nmmB, 256, 0, stream>>>(xb, wfr1, B1, hroot, N);
        for (int c = 0; c < nchunk; ++c) {
            int n_lo = c * npc;
            int n_hi = n_lo + npc; if (n_hi > N) n_hi = N;
            if (n_lo >= n_hi) break;
            gemm_kernel<128><<<gB, 256, 0, stream>>>(xb, es, nstart, wf1, C, n_lo, n_hi, CAP);
            reduce_kernel<<<rB, 256, 0, stream>>>(es, nstart, hroot, h1, C, n_lo, n_hi, CAP);
        }
        // layer 2
        rootmm_kernel<64><<<nmmB, 256, 0, stream>>>(h1, wfr2, B2, hroot, N);
        for (int c = 0; c < nchunk; ++c) {
            int n_lo = c * npc;
            int n_hi = n_lo + npc; if (n_hi > N) n_hi = N;
            if (n_lo >= n_hi) break;
            gemm_kernel<64><<<gB, 256, 0, stream>>>(h1, es, nstart, wf2, C, n_lo, n_hi, CAP);
            reduce_kernel<<<rB, 256, 0, stream>>>(es, nstart, hroot, h2, C, n_lo, n_hi, CAP);
        }
        // pool
        int pwaves = (N + 255) / 256;
        pool_kernel<<<(pwaves * 64 + 255) / 256, 256, 0, stream>>>(
            h2, batch, pool, gcnt, enc * 64, N);
    }

    depth_kernel<<<1, 512, 0, stream>>>(depth, dnorm, Bn);
    regress_kernel<<<(Bn * 64 + 255) / 256, 256, 0, stream>>>(
        pool, gcnt_s, gcnt_g, dnorm, rW1, rB1, rW2, rB2, pred, Bn);
}

// Round 8
// 1724.523 us; speedup vs baseline: 2.4484x; 1.0258x over previous
//
#include <hip/hip_runtime.h>

// N=100000 nodes, E=1600000 edges, IN=128, H=64, R=32, B=512
constexpr int HD    = 64;
constexpr int RNUM  = 32;
constexpr int WROWS = 512;    // CSR rows per gemm block (smaller -> more blocks)

typedef __attribute__((ext_vector_type(4))) float f32x4;
typedef __attribute__((ext_vector_type(8))) short bf16x8;

#define WS_ALIGN(x) (((x) + size_t(255)) & ~size_t(255))

__device__ inline float b2f(unsigned short u) {
    return __uint_as_float(((unsigned)u) << 16);
}
__device__ inline unsigned short f2b(float f) {
    unsigned u = __float_as_uint(f);
    u = (u + 0x7FFF + ((u >> 16) & 1)) >> 16;
    return (unsigned short)u;
}
__device__ inline unsigned pack2bf(float a, float b) {
    return (unsigned)f2b(a) | ((unsigned)f2b(b) << 16);
}

// ---------------- preprocessing ----------------

__global__ __launch_bounds__(256) void count_kernel(
    const int* __restrict__ dst, int* __restrict__ deg, int* __restrict__ rank, int E)
{
    int e = blockIdx.x * 256 + threadIdx.x;
    if (e < E) rank[e] = atomicAdd(&deg[dst[e]], 1);
}

__global__ __launch_bounds__(256) void scan1_kernel(
    const int* __restrict__ in, int* __restrict__ out, int* __restrict__ part, int n)
{
    __shared__ int ls[256];
    const int i0 = blockIdx.x * 1024 + threadIdx.x * 4;
    int v[4];
    int tot = 0;
#pragma unroll
    for (int u = 0; u < 4; ++u) {
        int x = (i0 + u < n) ? in[i0 + u] : 0;
        v[u] = tot;
        tot += x;
    }
    ls[threadIdx.x] = tot;
    __syncthreads();
    for (int off = 1; off < 256; off <<= 1) {
        int x = (threadIdx.x >= off) ? ls[threadIdx.x - off] : 0;
        __syncthreads();
        ls[threadIdx.x] += x;
        __syncthreads();
    }
    int texcl = ls[threadIdx.x] - tot;
#pragma unroll
    for (int u = 0; u < 4; ++u)
        if (i0 + u < n) out[i0 + u] = texcl + v[u];
    if (threadIdx.x == 255) part[blockIdx.x] = ls[255];
}

__global__ void scan2_kernel(int* __restrict__ part, int nb, int* __restrict__ out, int n)
{
    if (threadIdx.x == 0) {
        int acc = 0;
        for (int i = 0; i < nb; ++i) { int t = part[i]; part[i] = acc; acc += t; }
        out[n] = acc;
    }
}

__global__ __launch_bounds__(256) void scan3_kernel(
    int* __restrict__ out, const int* __restrict__ part, int n)
{
    int i = blockIdx.x * 256 + threadIdx.x;
    if (i < n) out[i] += part[blockIdx.x >> 2];
}

// CSR scatter: es[nstart[d]+rank[e]] = src | (type<<17)
__global__ __launch_bounds__(256) void scatter_kernel(
    const int* __restrict__ src, const int* __restrict__ dst, const int* __restrict__ et,
    const int* __restrict__ rank, const int* __restrict__ nstart,
    int* __restrict__ es, int E)
{
    int e = blockIdx.x * 256 + threadIdx.x;
    if (e < E)
        es[nstart[dst[e]] + rank[e]] = src[e] | (et[e] << 17);
}

__global__ __launch_bounds__(256) void tobf16_kernel(
    const float* __restrict__ in, unsigned short* __restrict__ out, int total8)
{
    int i = blockIdx.x * 256 + threadIdx.x;
    if (i >= total8) return;
    const float4* ip = (const float4*)(in + (size_t)i * 8);
    float4 a = ip[0], b = ip[1];
    uint4 o;
    o.x = pack2bf(a.x, a.y); o.y = pack2bf(a.z, a.w);
    o.z = pack2bf(b.x, b.y); o.w = pack2bf(b.z, b.w);
    *(uint4*)(out + (size_t)i * 8) = o;
}

// pre-permute W (32 relations) into MFMA A-fragment layout, bf16
template<int K>
__global__ __launch_bounds__(256) void wfrag_kernel(
    const float* __restrict__ W, unsigned short* __restrict__ wfrag)
{
    constexpr int KS = K / 32;
    int idx = blockIdx.x * 256 + threadIdx.x;
    int total = RNUM * KS * 4 * 64;
    if (idx >= total) return;
    int lane = idx & 63;
    int tmp = idx >> 6;
    int jt = tmp & 3; tmp >>= 2;
    int ks = tmp % KS;
    int t = tmp / KS;
    int col = jt * 16 + (lane & 15);
    int kb = ks * 32 + (lane >> 4) * 8;
    const float* Wp = W + ((size_t)t * K + kb) * HD + col;
    uint4 o;
    o.x = pack2bf(Wp[0 * HD], Wp[1 * HD]);
    o.y = pack2bf(Wp[2 * HD], Wp[3 * HD]);
    o.z = pack2bf(Wp[4 * HD], Wp[5 * HD]);
    o.w = pack2bf(Wp[6 * HD], Wp[7 * HD]);
    *(uint4*)(wfrag + (size_t)idx * 8) = o;
}

// same fragment permute for a single matrix (Wroot)
template<int K>
__global__ __launch_bounds__(256) void wfroot_kernel(
    const float* __restrict__ Root, unsigned short* __restrict__ wfr)
{
    constexpr int KS = K / 32;
    int idx = blockIdx.x * 256 + threadIdx.x;
    int total = KS * 4 * 64;
    if (idx >= total) return;
    int lane = idx & 63;
    int tmp = idx >> 6;
    int jt = tmp & 3;
    int ks = tmp >> 2;
    int col = jt * 16 + (lane & 15);
    int kb = ks * 32 + (lane >> 4) * 8;
    const float* Wp = Root + (size_t)kb * HD + col;
    uint4 o;
    o.x = pack2bf(Wp[0 * HD], Wp[1 * HD]);
    o.y = pack2bf(Wp[2 * HD], Wp[3 * HD]);
    o.z = pack2bf(Wp[4 * HD], Wp[5 * HD]);
    o.w = pack2bf(Wp[6 * HD], Wp[7 * HD]);
    *(uint4*)(wfr + (size_t)idx * 8) = o;
}

// dense MFMA GEMM: hroot[n][j] = bias[j] + sum_k x[n][k]*Root[k][j]  (bf16 out)
template<int K>
__global__ __launch_bounds__(256) void rootmm_kernel(
    const unsigned short* __restrict__ xb, const unsigned short* __restrict__ wfr,
    const float* __restrict__ bias, unsigned short* __restrict__ hroot, int N)
{
    constexpr int KS = K / 32;
    __shared__ unsigned short sW[KS * 4 * 64 * 8];
    __shared__ float sbias[HD];
    const int tid = threadIdx.x;
    for (int i = tid; i < KS * 256; i += 256)
        ((uint4*)sW)[i] = ((const uint4*)wfr)[i];
    if (tid < HD) sbias[tid] = bias[tid];
    __syncthreads();
    const int lane = tid & 63;
    const int wid = tid >> 6;
    const int jb = (lane >> 4) * 4;
#pragma unroll
    for (int b = 0; b < 4; ++b) {
        const int node0 = blockIdx.x * 256 + wid * 64 + b * 16;
        const int node = node0 + (lane & 15);
        const int nclamp = node < N ? node : N - 1;
        const unsigned short* xp = xb + (size_t)nclamp * K + (lane >> 4) * 8;
        f32x4 acc[4];
#pragma unroll
        for (int jt = 0; jt < 4; ++jt) acc[jt] = (f32x4)0.0f;
#pragma unroll
        for (int ks = 0; ks < KS; ++ks) {
            bf16x8 bx = *(const bf16x8*)(xp + ks * 32);
#pragma unroll
            for (int jt = 0; jt < 4; ++jt) {
                bf16x8 aw = *(const bf16x8*)(sW + (size_t)((ks * 4 + jt) * 64 + lane) * 8);
                acc[jt] = __builtin_amdgcn_mfma_f32_16x16x32_bf16(aw, bx, acc[jt], 0, 0, 0);
            }
        }
        if (node < N) {
            unsigned short* hr = hroot + (size_t)node * HD + jb;
#pragma unroll
            for (int jt = 0; jt < 4; ++jt) {
                const int j0 = jt * 16 + jb;
                uint2 pk;
                pk.x = pack2bf(acc[jt][0] + sbias[j0 + 0], acc[jt][1] + sbias[j0 + 1]);
                pk.y = pack2bf(acc[jt][2] + sbias[j0 + 2], acc[jt][3] + sbias[j0 + 3]);
                *(uint2*)(hr + jt * 16) = pk;
            }
        }
    }
}

// dst-major gather-GEMM with software-pipelined gathers:
// block owns a 512-row CSR window, counting-sorts its edges by type in LDS,
// runs 16-edge single-type MFMA batches with next-batch x-gathers prefetched,
// writes each message row once to its own C slot.
template<int K>
__global__ __launch_bounds__(256) void gemm_kernel(
    const unsigned short* __restrict__ xb, const int* __restrict__ es,
    const int* __restrict__ nstart, const unsigned short* __restrict__ wfrag,
    unsigned short* __restrict__ C, int n_lo, int n_hi, int cap)
{
    constexpr int KS = K / 32;
    __shared__ int s_es[WROWS];
    __shared__ unsigned short s_idx[WROWS];
    __shared__ int hist[RNUM], tbase[RNUM], tcur[RNUM];
    __shared__ int bdesc[WROWS / 16 + RNUM + 2];
    __shared__ int nb_s;
    const int tid = threadIdx.x;
    const int e_lo = nstart[n_lo];
    const int e_hi = nstart[n_hi];
    int rows = e_hi - e_lo;
    if (rows > cap) rows = cap;
    const int r0 = blockIdx.x * WROWS;
    if (r0 >= rows) return;
    const int rcnt = (WROWS < rows - r0) ? WROWS : (rows - r0);

    for (int i = tid; i < rcnt; i += 256) s_es[i] = es[e_lo + r0 + i];
    if (tid < RNUM) hist[tid] = 0;
    __syncthreads();
    for (int i = tid; i < rcnt; i += 256)
        atomicAdd(&hist[(s_es[i] >> 17) & 31], 1);
    __syncthreads();
    if (tid == 0) {
        int acc = 0, nb = 0;
        for (int t = 0; t < RNUM; ++t) {
            tbase[t] = acc;
            for (int c2 = 0; c2 < hist[t]; c2 += 16)
                bdesc[nb++] = (t << 10) | (acc + c2);
            acc += hist[t];
        }
        nb_s = nb;
    }
    __syncthreads();
    if (tid < RNUM) tcur[tid] = tbase[tid];
    __syncthreads();
    for (int i = tid; i < rcnt; i += 256) {
        int t = (s_es[i] >> 17) & 31;
        int pos = atomicAdd(&tcur[t], 1);
        s_idx[pos] = (unsigned short)i;
    }
    __syncthreads();

    const int nb = nb_s;
    const int lane = tid & 63;
    const int wid = tid >> 6;
    const int b0 = (nb * wid) >> 2;
    const int b1 = (nb * (wid + 1)) >> 2;
    if (b0 >= b1) return;

    // ---- software pipeline: prefetch next batch's gathers ----
    int t_c, idx_c;
    bool val_c;
    bf16x8 bx_c[KS];
    {
        const int desc = bdesc[b0];
        t_c = desc >> 10;
        const int p0 = desc & 1023;
        const int tend = tbase[t_c] + hist[t_c];
        const int c = p0 + (lane & 15);
        val_c = c < tend;
        idx_c = s_idx[val_c ? c : p0];
        const unsigned short* xp = xb + (size_t)(s_es[idx_c] & 0x1FFFF) * K + (lane >> 4) * 8;
#pragma unroll
        for (int ks = 0; ks < KS; ++ks) bx_c[ks] = *(const bf16x8*)(xp + ks * 32);
    }
    for (int bi = b0; bi < b1; ++bi) {
        int t_n = 0, idx_n = 0;
        bool val_n = false;
        bf16x8 bx_n[KS];
        if (bi + 1 < b1) {
            const int desc = bdesc[bi + 1];
            t_n = desc >> 10;
            const int p0 = desc & 1023;
            const int tend = tbase[t_n] + hist[t_n];
            const int c = p0 + (lane & 15);
            val_n = c < tend;
            idx_n = s_idx[val_n ? c : p0];
            const unsigned short* xp = xb + (size_t)(s_es[idx_n] & 0x1FFFF) * K + (lane >> 4) * 8;
#pragma unroll
            for (int ks = 0; ks < KS; ++ks) bx_n[ks] = *(const bf16x8*)(xp + ks * 32);
        }
        const unsigned short* wt = wfrag + (size_t)t_c * (KS * 2048);
        f32x4 acc[4];
#pragma unroll
        for (int jt = 0; jt < 4; ++jt) acc[jt] = (f32x4)0.0f;
#pragma unroll
        for (int ks = 0; ks < KS; ++ks) {
#pragma unroll
            for (int jt = 0; jt < 4; ++jt) {
                bf16x8 aw = *(const bf16x8*)(wt + (size_t)((ks * 4 + jt) * 64 + lane) * 8);
                acc[jt] = __builtin_amdgcn_mfma_f32_16x16x32_bf16(aw, bx_c[ks], acc[jt], 0, 0, 0);
            }
        }
        if (val_c) {
            unsigned short* cr = C + (size_t)(r0 + idx_c) * HD + (lane >> 4) * 4;
#pragma unroll
            for (int jt = 0; jt < 4; ++jt) {
                uint2 pk;
                pk.x = pack2bf(acc[jt][0], acc[jt][1]);
                pk.y = pack2bf(acc[jt][2], acc[jt][3]);
                *(uint2*)(cr + jt * 16) = pk;
            }
        }
        t_c = t_n; idx_c = idx_n; val_c = val_n;
#pragma unroll
        for (int ks = 0; ks < KS; ++ks) bx_c[ks] = bx_n[ks];
    }
}

// streaming per-node reduce: hroot + per-type means of C rows; relu -> bf16
__global__ __launch_bounds__(256) void reduce_kernel(
    const int* __restrict__ es, const int* __restrict__ nstart,
    const unsigned short* __restrict__ hroot, unsigned short* __restrict__ hout,
    const unsigned short* __restrict__ C, int n_lo, int n_hi, int cap)
{
    __shared__ int scnt[4][RNUM];
    __shared__ float sinv[4][RNUM];
    const int tid = threadIdx.x, lane = tid & 63, wid = tid >> 6;
    const int e_lo = nstart[n_lo];
    const int node = n_lo + blockIdx.x * 4 + wid;
    const bool active = node < n_hi;
    int rs = 0, re = 0;
    if (active) { rs = nstart[node]; re = nstart[node + 1]; }
    if (lane < RNUM) scnt[wid][lane] = 0;
    __syncthreads();
    for (int e = rs + lane; e < re; e += 64)
        atomicAdd(&scnt[wid][(es[e] >> 17) & 31], 1);
    __syncthreads();
    if (lane < RNUM) {
        int c = scnt[wid][lane];
        sinv[wid][lane] = 1.0f / (float)(c > 1 ? c : 1);
    }
    __syncthreads();
    if (!active) return;
    float acc = b2f(hroot[(size_t)node * HD + lane]);
    for (int e = rs; e < re; ++e) {
        int row = e - e_lo;
        float iv = sinv[wid][(es[e] >> 17) & 31];
        if ((unsigned)row < (unsigned)cap)
            acc += iv * b2f(C[(size_t)row * HD + lane]);
    }
    hout[(size_t)node * HD + lane] = f2b(fmaxf(acc, 0.f));
}

// mean-pool h per graph; batch sorted -> register run accumulation
__global__ __launch_bounds__(256) void pool_kernel(
    const unsigned short* __restrict__ h, const int* __restrict__ batch,
    float* __restrict__ pool, float* __restrict__ gcnt, int col0, int n)
{
    const int lane = threadIdx.x & 63;
    const int wid = (blockIdx.x * 256 + threadIdx.x) >> 6;
    const int RANGE = 256;
    int n0 = wid * RANGE;
    if (n0 >= n) return;
    int n1 = n0 + RANGE;
    if (n1 > n) n1 = n;
    int cur = batch[n0];
    float acc = 0.f, c = 0.f;
    for (int i = n0; i < n1; ++i) {
        int b = batch[i];
        if (b != cur) {
            unsafeAtomicAdd(&pool[(size_t)cur * 128 + col0 + lane], acc);
            if (lane == 0) unsafeAtomicAdd(&gcnt[cur], c);
            acc = 0.f; c = 0.f; cur = b;
        }
        acc += b2f(h[(size_t)i * HD + lane]);
        c += 1.f;
    }
    unsafeAtomicAdd(&pool[(size_t)cur * 128 + col0 + lane], acc);
    if (lane == 0) unsafeAtomicAdd(&gcnt[cur], c);
}

__global__ __launch_bounds__(512) void depth_kernel(
    const float* __restrict__ depth, float* __restrict__ dnorm, int Bn)
{
    __shared__ float ls[8];
    __shared__ float smean, sstd;
    const int t = threadIdx.x, lane = t & 63, wv = t >> 6;
    float d = (t < Bn) ? depth[t] : 0.f;
    float s = d;
#pragma unroll
    for (int o = 32; o; o >>= 1) s += __shfl_down(s, o, 64);
    if (lane == 0) ls[wv] = s;
    __syncthreads();
    if (t == 0) {
        float tot = 0.f;
        for (int i = 0; i < 8; ++i) tot += ls[i];
        smean = tot / (float)Bn;
    }
    __syncthreads();
    float mean = smean;
    float df = (t < Bn) ? (d - mean) : 0.f;
    s = df * df;
#pragma unroll
    for (int o = 32; o; o >>= 1) s += __shfl_down(s, o, 64);
    __syncthreads();
    if (lane == 0) ls[wv] = s;
    __syncthreads();
    if (t == 0) {
        float tot = 0.f;
        for (int i = 0; i < 8; ++i) tot += ls[i];
        sstd = sqrtf(tot / (float)Bn);
    }
    __syncthreads();
    if (t < Bn) dnorm[t] = df / (sstd + 1e-6f);
}

__global__ __launch_bounds__(256) void regress_kernel(
    const float* __restrict__ pool, const float* __restrict__ gcnt_s,
    const float* __restrict__ gcnt_g, const float* __restrict__ dnorm,
    const float* __restrict__ rW1, const float* __restrict__ rB1,
    const float* __restrict__ rW2, const float* __restrict__ rB2,
    float* __restrict__ pred, int Bn)
{
    const int lane = threadIdx.x & 63;
    const int g = (blockIdx.x * 256 + threadIdx.x) >> 6;
    if (g >= Bn) return;
    const float is = 1.f / fmaxf(gcnt_s[g], 1.f);
    const float ig = 1.f / fmaxf(gcnt_g[g], 1.f);
    const float* pr = pool + (size_t)g * 128;
    float acc = rB1[lane];
    for (int k = 0; k < 64; ++k)
        acc = fmaf(pr[k] * is, rW1[k * 64 + lane], acc);
    for (int k = 64; k < 128; ++k)
        acc = fmaf(pr[k] * ig, rW1[k * 64 + lane], acc);
    acc = fmaf(dnorm[g], rW1[128 * 64 + lane], acc);
    float v = fmaxf(acc, 0.f) * rW2[lane];
#pragma unroll
    for (int o = 32; o; o >>= 1) v += __shfl_down(v, o, 64);
    if (lane == 0) pred[g] = v + rB2[0];
}

// ---------------- launch ----------------

extern "C" void kernel_launch(void* const* d_in, const int* in_sizes, int n_in,
                              void* d_out, int out_size, void* d_ws, size_t ws_size,
                              hipStream_t stream)
{
    const int E1 = in_sizes[2];
    const int E2 = in_sizes[6];
    const int Emax = E1 > E2 ? E1 : E2;
    const int N = in_sizes[3];
    const int IN = in_sizes[0] / N;   // 128
    const int Bn = in_sizes[8];

    const float* state_x = (const float*)d_in[0];
    const int* s_ei = (const int*)d_in[1];
    const int* s_et = (const int*)d_in[2];
    const int* s_batch = (const int*)d_in[3];
    const float* goal_x = (const float*)d_in[4];
    const int* g_ei = (const int*)d_in[5];
    const int* g_et = (const int*)d_in[6];
    const int* g_batch = (const int*)d_in[7];
    const float* depth = (const float*)d_in[8];
    const float* sW1 = (const float*)d_in[9];
    const float* sRoot1 = (const float*)d_in[10];
    const float* sB1 = (const float*)d_in[11];
    const float* sW2 = (const float*)d_in[12];
    const float* sRoot2 = (const float*)d_in[13];
    const float* sB2 = (const float*)d_in[14];
    const float* gW1 = (const float*)d_in[15];
    const float* gRoot1 = (const float*)d_in[16];
    const float* gB1 = (const float*)d_in[17];
    const float* gW2 = (const float*)d_in[18];
    const float* gRoot2 = (const float*)d_in[19];
    const float* gB2 = (const float*)d_in[20];
    const float* rW1 = (const float*)d_in[21];
    const float* rB1 = (const float*)d_in[22];
    const float* rW2 = (const float*)d_in[23];
    const float* rB2 = (const float*)d_in[24];
    float* pred = (float*)d_out;

    const int nbScan = (N + 1023) / 1024;

    // fixed workspace budget
    size_t fixedb = 0;
    fixedb += WS_ALIGN((size_t)N * 4);              // deg
    fixedb += WS_ALIGN((size_t)(N + 1) * 4);        // nstart
    fixedb += WS_ALIGN((size_t)Emax * 4);           // rank
    fixedb += WS_ALIGN((size_t)nbScan * 4);         // part
    fixedb += WS_ALIGN((size_t)Emax * 4);           // es
    fixedb += WS_ALIGN((size_t)N * IN * 2);         // xb
    fixedb += WS_ALIGN((size_t)N * HD * 2);         // h1
    fixedb += WS_ALIGN((size_t)N * HD * 2);         // h2
    fixedb += WS_ALIGN((size_t)N * HD * 2);         // hroot
    fixedb += WS_ALIGN((size_t)RNUM * 4 * 4 * 64 * 8 * 2);  // wf1
    fixedb += WS_ALIGN((size_t)RNUM * 2 * 4 * 64 * 8 * 2);  // wf2
    fixedb += WS_ALIGN((size_t)4 * 4 * 64 * 8 * 2); // wfr1
    fixedb += WS_ALIGN((size_t)2 * 4 * 64 * 8 * 2); // wfr2
    fixedb += WS_ALIGN((size_t)Bn * 128 * 4);       // pool
    fixedb += 3 * WS_ALIGN((size_t)Bn * 4);         // gcnt_s, gcnt_g, dnorm

    size_t avail = (ws_size > fixedb + (size_t)(32 << 20))
                 ? ws_size - fixedb - (size_t)(32 << 20) : (size_t)(32 << 20);
    size_t capRows = avail / ((size_t)HD * 2);
    if (capRows > (size_t)Emax) capRows = (size_t)Emax;
    int nchunk = 1;
    if ((size_t)Emax > capRows) {
        nchunk = 2;
        while ((size_t)((double)Emax * 1.4 / nchunk) > capRows && nchunk < 256) nchunk++;
    }
    const int npc = (N + nchunk - 1) / nchunk;
    const int CAP = (int)capRows;
    const int gB = (int)((capRows + WROWS - 1) / WROWS);
    const int rB = (npc + 3) / 4;

    char* p = (char*)d_ws;
    auto alloc = [&](size_t bytes) { char* r = p; p += WS_ALIGN(bytes); return r; };
    int* deg    = (int*)alloc((size_t)N * 4);
    int* nstart = (int*)alloc((size_t)(N + 1) * 4);
    int* rank   = (int*)alloc((size_t)Emax * 4);
    int* part   = (int*)alloc((size_t)nbScan * 4);
    int* es     = (int*)alloc((size_t)Emax * 4);
    unsigned short* xb    = (unsigned short*)alloc((size_t)N * IN * 2);
    unsigned short* h1    = (unsigned short*)alloc((size_t)N * HD * 2);
    unsigned short* h2    = (unsigned short*)alloc((size_t)N * HD * 2);
    unsigned short* hroot = (unsigned short*)alloc((size_t)N * HD * 2);
    unsigned short* wf1   = (unsigned short*)alloc((size_t)RNUM * 4 * 4 * 64 * 8 * 2);
    unsigned short* wf2   = (unsigned short*)alloc((size_t)RNUM * 2 * 4 * 64 * 8 * 2);
    unsigned short* wfr1  = (unsigned short*)alloc((size_t)4 * 4 * 64 * 8 * 2);
    unsigned short* wfr2  = (unsigned short*)alloc((size_t)2 * 4 * 64 * 8 * 2);
    float* pool   = (float*)alloc((size_t)Bn * 128 * 4);
    float* gcnt_s = (float*)alloc((size_t)Bn * 4);
    float* gcnt_g = (float*)alloc((size_t)Bn * 4);
    float* dnorm  = (float*)alloc((size_t)Bn * 4);
    unsigned short* C = (unsigned short*)alloc(capRows * (size_t)HD * 2);

    hipMemsetAsync(pool, 0, (size_t)Bn * 128 * 4, stream);
    hipMemsetAsync(gcnt_s, 0, (size_t)Bn * 4, stream);
    hipMemsetAsync(gcnt_g, 0, (size_t)Bn * 4, stream);

    const int nmmB = (N + 255) / 256;

    for (int enc = 0; enc < 2; ++enc) {
        const float* x = enc ? goal_x : state_x;
        const int* ei = enc ? g_ei : s_ei;
        const int* et = enc ? g_et : s_et;
        const int* batch = enc ? g_batch : s_batch;
        const float* W1 = enc ? gW1 : sW1;
        const float* Root1 = enc ? gRoot1 : sRoot1;
        const float* B1 = enc ? gB1 : sB1;
        const float* W2 = enc ? gW2 : sW2;
        const float* Root2 = enc ? gRoot2 : sRoot2;
        const float* B2 = enc ? gB2 : sB2;
        float* gcnt = enc ? gcnt_g : gcnt_s;
        const int E = enc ? E2 : E1;
        const int* srcp = ei;
        const int* dstp = ei + E;
        const int ebl = (E + 255) / 256;

        hipMemsetAsync(deg, 0, (size_t)N * 4, stream);

        count_kernel<<<ebl, 256, 0, stream>>>(dstp, deg, rank, E);
        scan1_kernel<<<nbScan, 256, 0, stream>>>(deg, nstart, part, N);
        scan2_kernel<<<1, 64, 0, stream>>>(part, nbScan, nstart, N);
        scan3_kernel<<<nbScan * 4, 256, 0, stream>>>(nstart, part, N);
        scatter_kernel<<<ebl, 256, 0, stream>>>(srcp, dstp, et, rank, nstart, es, E);

        tobf16_kernel<<<(N * IN / 8 + 255) / 256, 256, 0, stream>>>(x, xb, N * IN / 8);
        wfrag_kernel<128><<<(RNUM * 4 * 4 * 64 + 255) / 256, 256, 0, stream>>>(W1, wf1);
        wfrag_kernel<64><<<(RNUM * 2 * 4 * 64 + 255) / 256, 256, 0, stream>>>(W2, wf2);
        wfroot_kernel<128><<<(4 * 4 * 64 + 255) / 256, 256, 0, stream>>>(Root1, wfr1);
        wfroot_kernel<64><<<(2 * 4 * 64 + 255) / 256, 256, 0, stream>>>(Root2, wfr2);

        // layer 1
        rootmm_kernel<128><<<nmmB, 256, 0, stream>>>(xb, wfr1, B1, hroot, N);
        for (int c = 0; c < nchunk; ++c) {
            int n_lo = c * npc;
            int n_hi = n_lo + npc; if (n_hi > N) n_hi = N;
            if (n_lo >= n_hi) break;
            gemm_kernel<128><<<gB, 256, 0, stream>>>(xb, es, nstart, wf1, C, n_lo, n_hi, CAP);
            reduce_kernel<<<rB, 256, 0, stream>>>(es, nstart, hroot, h1, C, n_lo, n_hi, CAP);
        }
        // layer 2
        rootmm_kernel<64><<<nmmB, 256, 0, stream>>>(h1, wfr2, B2, hroot, N);
        for (int c = 0; c < nchunk; ++c) {
            int n_lo = c * npc;
            int n_hi = n_lo + npc; if (n_hi > N) n_hi = N;
            if (n_lo >= n_hi) break;
            gemm_kernel<64><<<gB, 256, 0, stream>>>(h1, es, nstart, wf2, C, n_lo, n_hi, CAP);
            reduce_kernel<<<rB, 256, 0, stream>>>(es, nstart, hroot, h2, C, n_lo, n_hi, CAP);
        }
        // pool
        int pwaves = (N + 255) / 256;
        pool_kernel<<<(pwaves * 64 + 255) / 256, 256, 0, stream>>>(
            h2, batch, pool, gcnt, enc * 64, N);
    }

    depth_kernel<<<1, 512, 0, stream>>>(depth, dnorm, Bn);
    regress_kernel<<<(Bn * 64 + 255) / 256, 256, 0, stream>>>(
        pool, gcnt_s, gcnt_g, dnorm, rW1, rB1, rW2, rB2, pred, Bn);
}

// Round 9
// 1642.313 us; speedup vs baseline: 2.5709x; 1.0501x over previous
//
#include <hip/hip_runtime.h>

// N=100000 nodes, E=1600000 edges, IN=128, H=64, R=32, B=512
constexpr int HD     = 64;
constexpr int RNUM   = 32;
constexpr int STRIDE = 512;   // target edges per fused block
constexpr int CAPE   = 576;   // LDS msg rows (>= STRIDE + max boundary degree)

typedef __attribute__((ext_vector_type(4))) float f32x4;
typedef __attribute__((ext_vector_type(8))) short bf16x8;

#define WS_ALIGN(x) (((x) + size_t(255)) & ~size_t(255))

__device__ inline float b2f(unsigned short u) {
    return __uint_as_float(((unsigned)u) << 16);
}
__device__ inline unsigned short f2b(float f) {
    unsigned u = __float_as_uint(f);
    u = (u + 0x7FFF + ((u >> 16) & 1)) >> 16;
    return (unsigned short)u;
}
__device__ inline unsigned pack2bf(float a, float b) {
    return (unsigned)f2b(a) | ((unsigned)f2b(b) << 16);
}

// ---------------- preprocessing ----------------

__global__ __launch_bounds__(256) void count_kernel(
    const int* __restrict__ dst, int* __restrict__ deg, int* __restrict__ rank, int E)
{
    int e = blockIdx.x * 256 + threadIdx.x;
    if (e < E) rank[e] = atomicAdd(&deg[dst[e]], 1);
}

__global__ __launch_bounds__(256) void scan1_kernel(
    const int* __restrict__ in, int* __restrict__ out, int* __restrict__ part, int n)
{
    __shared__ int ls[256];
    const int i0 = blockIdx.x * 1024 + threadIdx.x * 4;
    int v[4];
    int tot = 0;
#pragma unroll
    for (int u = 0; u < 4; ++u) {
        int x = (i0 + u < n) ? in[i0 + u] : 0;
        v[u] = tot;
        tot += x;
    }
    ls[threadIdx.x] = tot;
    __syncthreads();
    for (int off = 1; off < 256; off <<= 1) {
        int x = (threadIdx.x >= off) ? ls[threadIdx.x - off] : 0;
        __syncthreads();
        ls[threadIdx.x] += x;
        __syncthreads();
    }
    int texcl = ls[threadIdx.x] - tot;
#pragma unroll
    for (int u = 0; u < 4; ++u)
        if (i0 + u < n) out[i0 + u] = texcl + v[u];
    if (threadIdx.x == 255) part[blockIdx.x] = ls[255];
}

__global__ void scan2_kernel(int* __restrict__ part, int nb, int* __restrict__ out, int n)
{
    if (threadIdx.x == 0) {
        int acc = 0;
        for (int i = 0; i < nb; ++i) { int t = part[i]; part[i] = acc; acc += t; }
        out[n] = acc;
    }
}

__global__ __launch_bounds__(256) void scan3_kernel(
    int* __restrict__ out, const int* __restrict__ part, int n)
{
    int i = blockIdx.x * 256 + threadIdx.x;
    if (i < n) out[i] += part[blockIdx.x >> 2];
}

// bstart[b] = first node n with nstart[n] >= b*STRIDE
__global__ __launch_bounds__(256) void boundary_kernel(
    const int* __restrict__ nstart, int* __restrict__ bstart, int N, int nblk)
{
    int b = blockIdx.x * 256 + threadIdx.x;
    if (b > nblk) return;
    if (b == nblk) { bstart[b] = N; return; }
    int target = b * STRIDE;
    int lo = 0, hi = N;
    while (lo < hi) {
        int mid = (lo + hi) >> 1;
        if (nstart[mid] < target) lo = mid + 1; else hi = mid;
    }
    bstart[b] = lo;
}

// CSR scatter: es[nstart[d]+rank[e]] = src | (type<<17)
__global__ __launch_bounds__(256) void scatter_kernel(
    const int* __restrict__ src, const int* __restrict__ dst, const int* __restrict__ et,
    const int* __restrict__ rank, const int* __restrict__ nstart,
    int* __restrict__ es, int E)
{
    int e = blockIdx.x * 256 + threadIdx.x;
    if (e < E)
        es[nstart[dst[e]] + rank[e]] = src[e] | (et[e] << 17);
}

__global__ __launch_bounds__(256) void tobf16_kernel(
    const float* __restrict__ in, unsigned short* __restrict__ out, int total8)
{
    int i = blockIdx.x * 256 + threadIdx.x;
    if (i >= total8) return;
    const float4* ip = (const float4*)(in + (size_t)i * 8);
    float4 a = ip[0], b = ip[1];
    uint4 o;
    o.x = pack2bf(a.x, a.y); o.y = pack2bf(a.z, a.w);
    o.z = pack2bf(b.x, b.y); o.w = pack2bf(b.z, b.w);
    *(uint4*)(out + (size_t)i * 8) = o;
}

// pre-permute W (32 relations) into MFMA A-fragment layout, bf16
template<int K>
__global__ __launch_bounds__(256) void wfrag_kernel(
    const float* __restrict__ W, unsigned short* __restrict__ wfrag)
{
    constexpr int KS = K / 32;
    int idx = blockIdx.x * 256 + threadIdx.x;
    int total = RNUM * KS * 4 * 64;
    if (idx >= total) return;
    int lane = idx & 63;
    int tmp = idx >> 6;
    int jt = tmp & 3; tmp >>= 2;
    int ks = tmp % KS;
    int t = tmp / KS;
    int col = jt * 16 + (lane & 15);
    int kb = ks * 32 + (lane >> 4) * 8;
    const float* Wp = W + ((size_t)t * K + kb) * HD + col;
    uint4 o;
    o.x = pack2bf(Wp[0 * HD], Wp[1 * HD]);
    o.y = pack2bf(Wp[2 * HD], Wp[3 * HD]);
    o.z = pack2bf(Wp[4 * HD], Wp[5 * HD]);
    o.w = pack2bf(Wp[6 * HD], Wp[7 * HD]);
    *(uint4*)(wfrag + (size_t)idx * 8) = o;
}

// same fragment permute for a single matrix (Wroot)
template<int K>
__global__ __launch_bounds__(256) void wfroot_kernel(
    const float* __restrict__ Root, unsigned short* __restrict__ wfr)
{
    constexpr int KS = K / 32;
    int idx = blockIdx.x * 256 + threadIdx.x;
    int total = KS * 4 * 64;
    if (idx >= total) return;
    int lane = idx & 63;
    int tmp = idx >> 6;
    int jt = tmp & 3;
    int ks = tmp >> 2;
    int col = jt * 16 + (lane & 15);
    int kb = ks * 32 + (lane >> 4) * 8;
    const float* Wp = Root + (size_t)kb * HD + col;
    uint4 o;
    o.x = pack2bf(Wp[0 * HD], Wp[1 * HD]);
    o.y = pack2bf(Wp[2 * HD], Wp[3 * HD]);
    o.z = pack2bf(Wp[4 * HD], Wp[5 * HD]);
    o.w = pack2bf(Wp[6 * HD], Wp[7 * HD]);
    *(uint4*)(wfr + (size_t)idx * 8) = o;
}

// dense MFMA GEMM: hroot[n][j] = bias[j] + sum_k x[n][k]*Root[k][j]  (bf16 out)
template<int K>
__global__ __launch_bounds__(256) void rootmm_kernel(
    const unsigned short* __restrict__ xb, const unsigned short* __restrict__ wfr,
    const float* __restrict__ bias, unsigned short* __restrict__ hroot, int N)
{
    constexpr int KS = K / 32;
    __shared__ unsigned short sW[KS * 4 * 64 * 8];
    __shared__ float sbias[HD];
    const int tid = threadIdx.x;
    for (int i = tid; i < KS * 256; i += 256)
        ((uint4*)sW)[i] = ((const uint4*)wfr)[i];
    if (tid < HD) sbias[tid] = bias[tid];
    __syncthreads();
    const int lane = tid & 63;
    const int wid = tid >> 6;
    const int jb = (lane >> 4) * 4;
#pragma unroll
    for (int b = 0; b < 4; ++b) {
        const int node = blockIdx.x * 256 + wid * 64 + b * 16 + (lane & 15);
        const int nclamp = node < N ? node : N - 1;
        const unsigned short* xp = xb + (size_t)nclamp * K + (lane >> 4) * 8;
        f32x4 acc[4];
#pragma unroll
        for (int jt = 0; jt < 4; ++jt) acc[jt] = (f32x4)0.0f;
#pragma unroll
        for (int ks = 0; ks < KS; ++ks) {
            bf16x8 bx = *(const bf16x8*)(xp + ks * 32);
#pragma unroll
            for (int jt = 0; jt < 4; ++jt) {
                bf16x8 aw = *(const bf16x8*)(sW + (size_t)((ks * 4 + jt) * 64 + lane) * 8);
                acc[jt] = __builtin_amdgcn_mfma_f32_16x16x32_bf16(aw, bx, acc[jt], 0, 0, 0);
            }
        }
        if (node < N) {
            unsigned short* hr = hroot + (size_t)node * HD + jb;
#pragma unroll
            for (int jt = 0; jt < 4; ++jt) {
                const int j0 = jt * 16 + jb;
                uint2 pk;
                pk.x = pack2bf(acc[jt][0] + sbias[j0 + 0], acc[jt][1] + sbias[j0 + 1]);
                pk.y = pack2bf(acc[jt][2] + sbias[j0 + 2], acc[jt][3] + sbias[j0 + 3]);
                *(uint2*)(hr + jt * 16) = pk;
            }
        }
    }
}

// fused RGCN layer: node-aligned window, in-LDS type sort, MFMA message batches
// stored to LDS msg (XOR-swizzled rows, no atomics), then per-node segmented
// mean + hroot + relu -> h. No global message buffer.
template<int K>
__global__ __launch_bounds__(256) void fused_kernel(
    const unsigned short* __restrict__ xb, const int* __restrict__ es,
    const int* __restrict__ nstart, const int* __restrict__ bstart,
    const unsigned short* __restrict__ wfrag,
    const unsigned short* __restrict__ hroot,
    unsigned short* __restrict__ hout)
{
    constexpr int KS = K / 32;
    __shared__ unsigned short msg[CAPE * HD];   // 72 KB
    __shared__ int s_es[CAPE];
    __shared__ unsigned short s_idx[CAPE];
    __shared__ int hist[RNUM], tbase[RNUM], tcur[RNUM];
    __shared__ int bdesc[CAPE / 16 + RNUM + 2];
    __shared__ int nb_s, nend_s;
    __shared__ int scnt[4][RNUM];
    __shared__ float sinv[4][RNUM];

    const int tid = threadIdx.x, lane = tid & 63, wid = tid >> 6;
    int n0 = bstart[blockIdx.x];
    const int n1 = bstart[blockIdx.x + 1];

    while (n0 < n1) {
        // wave-0 cooperative greedy pack: nodes [n0, nend) with <= CAPE edges
        if (wid == 0) {
            const int ea_ = nstart[n0];
            int m = n0;
            for (;;) {
                int cand = m + 1 + lane;
                bool ok = (cand <= n1) && (nstart[cand] - ea_ <= CAPE);
                unsigned long long mm = __ballot(ok);
                int f = (~mm == 0ULL) ? 64 : (__ffsll((unsigned long long)(~mm)) - 1);
                m += f;
                if (f < 64 || m >= n1) break;
            }
            if (m == n0) m = n0 + 1;          // single node with deg > CAPE: clamp
            if (m > n1) m = n1;
            if (lane == 0) nend_s = m;
        }
        __syncthreads();
        const int na = n0, nb = nend_s;
        const int ea = nstart[na];
        int cnt = nstart[nb] - ea;
        if (cnt > CAPE) cnt = CAPE;

        // stage + type counting sort (int LDS atomics only)
        for (int i = tid; i < cnt; i += 256) s_es[i] = es[ea + i];
        if (tid < RNUM) hist[tid] = 0;
        __syncthreads();
        for (int i = tid; i < cnt; i += 256)
            atomicAdd(&hist[(s_es[i] >> 17) & 31], 1);
        __syncthreads();
        if (tid == 0) {
            int acc = 0, nbt = 0;
            for (int t = 0; t < RNUM; ++t) {
                tbase[t] = acc;
                for (int c2 = 0; c2 < hist[t]; c2 += 16)
                    bdesc[nbt++] = (t << 10) | (acc + c2);
                acc += hist[t];
            }
            nb_s = nbt;
        }
        __syncthreads();
        if (tid < RNUM) tcur[tid] = tbase[tid];
        __syncthreads();
        for (int i = tid; i < cnt; i += 256) {
            int t = (s_es[i] >> 17) & 31;
            s_idx[atomicAdd(&tcur[t], 1)] = (unsigned short)i;
        }
        __syncthreads();

        // MFMA phase: 16-edge single-type batches, prefetch pipeline,
        // store D rows to msg[orig_idx] with XOR swizzle
        {
            const int nbt = nb_s;
            const int b0 = (nbt * wid) >> 2;
            const int b1 = (nbt * (wid + 1)) >> 2;
            if (b0 < b1) {
                int t_c, idx_c;
                bool val_c;
                bf16x8 bx_c[KS];
                {
                    const int desc = bdesc[b0];
                    t_c = desc >> 10;
                    const int p0 = desc & 1023;
                    const int tend = tbase[t_c] + hist[t_c];
                    const int c = p0 + (lane & 15);
                    val_c = c < tend;
                    idx_c = s_idx[val_c ? c : p0];
                    const unsigned short* xp =
                        xb + (size_t)(s_es[idx_c] & 0x1FFFF) * K + (lane >> 4) * 8;
#pragma unroll
                    for (int ks = 0; ks < KS; ++ks) bx_c[ks] = *(const bf16x8*)(xp + ks * 32);
                }
                for (int bi = b0; bi < b1; ++bi) {
                    int t_n = 0, idx_n = 0;
                    bool val_n = false;
                    bf16x8 bx_n[KS];
                    if (bi + 1 < b1) {
                        const int desc = bdesc[bi + 1];
                        t_n = desc >> 10;
                        const int p0 = desc & 1023;
                        const int tend = tbase[t_n] + hist[t_n];
                        const int c = p0 + (lane & 15);
                        val_n = c < tend;
                        idx_n = s_idx[val_n ? c : p0];
                        const unsigned short* xp =
                            xb + (size_t)(s_es[idx_n] & 0x1FFFF) * K + (lane >> 4) * 8;
#pragma unroll
                        for (int ks = 0; ks < KS; ++ks) bx_n[ks] = *(const bf16x8*)(xp + ks * 32);
                    }
                    const unsigned short* wt = wfrag + (size_t)t_c * (KS * 2048);
                    f32x4 acc[4];
#pragma unroll
                    for (int jt = 0; jt < 4; ++jt) acc[jt] = (f32x4)0.0f;
#pragma unroll
                    for (int ks = 0; ks < KS; ++ks) {
#pragma unroll
                        for (int jt = 0; jt < 4; ++jt) {
                            bf16x8 aw = *(const bf16x8*)(wt + (size_t)((ks * 4 + jt) * 64 + lane) * 8);
                            acc[jt] = __builtin_amdgcn_mfma_f32_16x16x32_bf16(aw, bx_c[ks], acc[jt], 0, 0, 0);
                        }
                    }
                    if (val_c) {
                        char* mr = (char*)(msg + idx_c * HD);
                        const int swz = (idx_c & 7) << 4;
#pragma unroll
                        for (int jt = 0; jt < 4; ++jt) {
                            uint2 pk;
                            pk.x = pack2bf(acc[jt][0], acc[jt][1]);
                            pk.y = pack2bf(acc[jt][2], acc[jt][3]);
                            *(uint2*)(mr + (((lane >> 4) * 8 + jt * 32) ^ swz)) = pk;
                        }
                    }
                    t_c = t_n; idx_c = idx_n; val_c = val_n;
#pragma unroll
                    for (int ks = 0; ks < KS; ++ks) bx_c[ks] = bx_n[ks];
                }
            }
        }
        __syncthreads();

        // reduce phase: each wave owns whole nodes; rows contiguous in msg
        for (int n = na + wid; n < nb; n += 4) {
            const int rs = nstart[n] - ea;
            int re = nstart[n + 1] - ea;
            if (re > cnt) re = cnt;
            if (lane < RNUM) scnt[wid][lane] = 0;
            for (int e = rs + lane; e < re; e += 64)
                atomicAdd(&scnt[wid][(s_es[e] >> 17) & 31], 1);
            if (lane < RNUM) {
                int c = scnt[wid][lane];
                sinv[wid][lane] = 1.0f / (float)(c > 1 ? c : 1);
            }
            float acc = b2f(hroot[(size_t)n * HD + lane]);
            for (int e = rs; e < re; ++e) {
                const float iv = sinv[wid][(s_es[e] >> 17) & 31];
                const char* mr = (const char*)(msg + e * HD);
                acc += iv * b2f(*(const unsigned short*)(mr + ((lane * 2) ^ ((e & 7) << 4))));
            }
            hout[(size_t)n * HD + lane] = f2b(fmaxf(acc, 0.f));
        }
        __syncthreads();
        n0 = nb;
    }
}

// mean-pool h per graph; batch sorted -> register run accumulation
__global__ __launch_bounds__(256) void pool_kernel(
    const unsigned short* __restrict__ h, const int* __restrict__ batch,
    float* __restrict__ pool, float* __restrict__ gcnt, int col0, int n)
{
    const int lane = threadIdx.x & 63;
    const int wid = (blockIdx.x * 256 + threadIdx.x) >> 6;
    const int RANGE = 256;
    int n0 = wid * RANGE;
    if (n0 >= n) return;
    int n1 = n0 + RANGE;
    if (n1 > n) n1 = n;
    int cur = batch[n0];
    float acc = 0.f, c = 0.f;
    for (int i = n0; i < n1; ++i) {
        int b = batch[i];
        if (b != cur) {
            unsafeAtomicAdd(&pool[(size_t)cur * 128 + col0 + lane], acc);
            if (lane == 0) unsafeAtomicAdd(&gcnt[cur], c);
            acc = 0.f; c = 0.f; cur = b;
        }
        acc += b2f(h[(size_t)i * HD + lane]);
        c += 1.f;
    }
    unsafeAtomicAdd(&pool[(size_t)cur * 128 + col0 + lane], acc);
    if (lane == 0) unsafeAtomicAdd(&gcnt[cur], c);
}

__global__ __launch_bounds__(512) void depth_kernel(
    const float* __restrict__ depth, float* __restrict__ dnorm, int Bn)
{
    __shared__ float ls[8];
    __shared__ float smean, sstd;
    const int t = threadIdx.x, lane = t & 63, wv = t >> 6;
    float d = (t < Bn) ? depth[t] : 0.f;
    float s = d;
#pragma unroll
    for (int o = 32; o; o >>= 1) s += __shfl_down(s, o, 64);
    if (lane == 0) ls[wv] = s;
    __syncthreads();
    if (t == 0) {
        float tot = 0.f;
        for (int i = 0; i < 8; ++i) tot += ls[i];
        smean = tot / (float)Bn;
    }
    __syncthreads();
    float mean = smean;
    float df = (t < Bn) ? (d - mean) : 0.f;
    s = df * df;
#pragma unroll
    for (int o = 32; o; o >>= 1) s += __shfl_down(s, o, 64);
    __syncthreads();
    if (lane == 0) ls[wv] = s;
    __syncthreads();
    if (t == 0) {
        float tot = 0.f;
        for (int i = 0; i < 8; ++i) tot += ls[i];
        sstd = sqrtf(tot / (float)Bn);
    }
    __syncthreads();
    if (t < Bn) dnorm[t] = df / (sstd + 1e-6f);
}

__global__ __launch_bounds__(256) void regress_kernel(
    const float* __restrict__ pool, const float* __restrict__ gcnt_s,
    const float* __restrict__ gcnt_g, const float* __restrict__ dnorm,
    const float* __restrict__ rW1, const float* __restrict__ rB1,
    const float* __restrict__ rW2, const float* __restrict__ rB2,
    float* __restrict__ pred, int Bn)
{
    const int lane = threadIdx.x & 63;
    const int g = (blockIdx.x * 256 + threadIdx.x) >> 6;
    if (g >= Bn) return;
    const float is = 1.f / fmaxf(gcnt_s[g], 1.f);
    const float ig = 1.f / fmaxf(gcnt_g[g], 1.f);
    const float* pr = pool + (size_t)g * 128;
    float acc = rB1[lane];
    for (int k = 0; k < 64; ++k)
        acc = fmaf(pr[k] * is, rW1[k * 64 + lane], acc);
    for (int k = 64; k < 128; ++k)
        acc = fmaf(pr[k] * ig, rW1[k * 64 + lane], acc);
    acc = fmaf(dnorm[g], rW1[128 * 64 + lane], acc);
    float v = fmaxf(acc, 0.f) * rW2[lane];
#pragma unroll
    for (int o = 32; o; o >>= 1) v += __shfl_down(v, o, 64);
    if (lane == 0) pred[g] = v + rB2[0];
}

// ---------------- launch ----------------

extern "C" void kernel_launch(void* const* d_in, const int* in_sizes, int n_in,
                              void* d_out, int out_size, void* d_ws, size_t ws_size,
                              hipStream_t stream)
{
    const int E1 = in_sizes[2];
    const int E2 = in_sizes[6];
    const int Emax = E1 > E2 ? E1 : E2;
    const int N = in_sizes[3];
    const int IN = in_sizes[0] / N;   // 128
    const int Bn = in_sizes[8];

    const float* state_x = (const float*)d_in[0];
    const int* s_ei = (const int*)d_in[1];
    const int* s_et = (const int*)d_in[2];
    const int* s_batch = (const int*)d_in[3];
    const float* goal_x = (const float*)d_in[4];
    const int* g_ei = (const int*)d_in[5];
    const int* g_et = (const int*)d_in[6];
    const int* g_batch = (const int*)d_in[7];
    const float* depth = (const float*)d_in[8];
    const float* sW1 = (const float*)d_in[9];
    const float* sRoot1 = (const float*)d_in[10];
    const float* sB1 = (const float*)d_in[11];
    const float* sW2 = (const float*)d_in[12];
    const float* sRoot2 = (const float*)d_in[13];
    const float* sB2 = (const float*)d_in[14];
    const float* gW1 = (const float*)d_in[15];
    const float* gRoot1 = (const float*)d_in[16];
    const float* gB1 = (const float*)d_in[17];
    const float* gW2 = (const float*)d_in[18];
    const float* gRoot2 = (const float*)d_in[19];
    const float* gB2 = (const float*)d_in[20];
    const float* rW1 = (const float*)d_in[21];
    const float* rB1 = (const float*)d_in[22];
    const float* rW2 = (const float*)d_in[23];
    const float* rB2 = (const float*)d_in[24];
    float* pred = (float*)d_out;

    const int nbScan = (N + 1023) / 1024;
    const int nblkMax = (Emax + STRIDE - 1) / STRIDE;

    char* p = (char*)d_ws;
    auto alloc = [&](size_t bytes) { char* r = p; p += WS_ALIGN(bytes); return r; };
    int* deg    = (int*)alloc((size_t)N * 4);
    int* nstart = (int*)alloc((size_t)(N + 1) * 4);
    int* rank   = (int*)alloc((size_t)Emax * 4);
    int* part   = (int*)alloc((size_t)nbScan * 4);
    int* bstart = (int*)alloc((size_t)(nblkMax + 1) * 4);
    int* es     = (int*)alloc((size_t)Emax * 4);
    unsigned short* xb    = (unsigned short*)alloc((size_t)N * IN * 2);
    unsigned short* h1    = (unsigned short*)alloc((size_t)N * HD * 2);
    unsigned short* h2    = (unsigned short*)alloc((size_t)N * HD * 2);
    unsigned short* hroot = (unsigned short*)alloc((size_t)N * HD * 2);
    unsigned short* wf1   = (unsigned short*)alloc((size_t)RNUM * 4 * 4 * 64 * 8 * 2);
    unsigned short* wf2   = (unsigned short*)alloc((size_t)RNUM * 2 * 4 * 64 * 8 * 2);
    unsigned short* wfr1  = (unsigned short*)alloc((size_t)4 * 4 * 64 * 8 * 2);
    unsigned short* wfr2  = (unsigned short*)alloc((size_t)2 * 4 * 64 * 8 * 2);
    float* pool   = (float*)alloc((size_t)Bn * 128 * 4);
    float* gcnt_s = (float*)alloc((size_t)Bn * 4);
    float* gcnt_g = (float*)alloc((size_t)Bn * 4);
    float* dnorm  = (float*)alloc((size_t)Bn * 4);

    hipMemsetAsync(pool, 0, (size_t)Bn * 128 * 4, stream);
    hipMemsetAsync(gcnt_s, 0, (size_t)Bn * 4, stream);
    hipMemsetAsync(gcnt_g, 0, (size_t)Bn * 4, stream);

    const int nmmB = (N + 255) / 256;

    for (int enc = 0; enc < 2; ++enc) {
        const float* x = enc ? goal_x : state_x;
        const int* ei = enc ? g_ei : s_ei;
        const int* et = enc ? g_et : s_et;
        const int* batch = enc ? g_batch : s_batch;
        const float* W1 = enc ? gW1 : sW1;
        const float* Root1 = enc ? gRoot1 : sRoot1;
        const float* B1 = enc ? gB1 : sB1;
        const float* W2 = enc ? gW2 : sW2;
        const float* Root2 = enc ? gRoot2 : sRoot2;
        const float* B2 = enc ? gB2 : sB2;
        float* gcnt = enc ? gcnt_g : gcnt_s;
        const int E = enc ? E2 : E1;
        const int* srcp = ei;
        const int* dstp = ei + E;
        const int ebl = (E + 255) / 256;
        const int nblk = (E + STRIDE - 1) / STRIDE;

        hipMemsetAsync(deg, 0, (size_t)N * 4, stream);

        count_kernel<<<ebl, 256, 0, stream>>>(dstp, deg, rank, E);
        scan1_kernel<<<nbScan, 256, 0, stream>>>(deg, nstart, part, N);
        scan2_kernel<<<1, 64, 0, stream>>>(part, nbScan, nstart, N);
        scan3_kernel<<<nbScan * 4, 256, 0, stream>>>(nstart, part, N);
        boundary_kernel<<<(nblk + 1 + 255) / 256, 256, 0, stream>>>(nstart, bstart, N, nblk);
        scatter_kernel<<<ebl, 256, 0, stream>>>(srcp, dstp, et, rank, nstart, es, E);

        tobf16_kernel<<<(N * IN / 8 + 255) / 256, 256, 0, stream>>>(x, xb, N * IN / 8);
        wfrag_kernel<128><<<(RNUM * 4 * 4 * 64 + 255) / 256, 256, 0, stream>>>(W1, wf1);
        wfrag_kernel<64><<<(RNUM * 2 * 4 * 64 + 255) / 256, 256, 0, stream>>>(W2, wf2);
        wfroot_kernel<128><<<(4 * 4 * 64 + 255) / 256, 256, 0, stream>>>(Root1, wfr1);
        wfroot_kernel<64><<<(2 * 4 * 64 + 255) / 256, 256, 0, stream>>>(Root2, wfr2);

        // layer 1
        rootmm_kernel<128><<<nmmB, 256, 0, stream>>>(xb, wfr1, B1, hroot, N);
        fused_kernel<128><<<nblk, 256, 0, stream>>>(xb, es, nstart, bstart, wf1, hroot, h1);
        // layer 2
        rootmm_kernel<64><<<nmmB, 256, 0, stream>>>(h1, wfr2, B2, hroot, N);
        fused_kernel<64><<<nblk, 256, 0, stream>>>(h1, es, nstart, bstart, wf2, hroot, h2);

        // pool
        int pwaves = (N + 255) / 256;
        pool_kernel<<<(pwaves * 64 + 255) / 256, 256, 0, stream>>>(
            h2, batch, pool, gcnt, enc * 64, N);
    }

    depth_kernel<<<1, 512, 0, stream>>>(depth, dnorm, Bn);
    regress_kernel<<<(Bn * 64 + 255) / 256, 256, 0, stream>>>(
        pool, gcnt_s, gcnt_g, dnorm, rW1, rB1, rW2, rB2, pred, Bn);
}